// Round 1
// baseline (899.146 us; speedup 1.0000x reference)
//
#include <hip/hip_runtime.h>
#include <math.h>

#ifndef M_PI
#define M_PI 3.14159265358979323846
#endif

static inline int cdiv(int a, int b){ return (a + b - 1) / b; }

#define SQRT3f  1.7320508075688772f
#define SQRT5f  2.23606797749979f
#define SQRT15f 3.872983346207417f
#define KRADf   0.6324555320336759f      /* sqrt(2/R_MAX), R_MAX=5 */
#define PI5f    0.6283185307179586f      /* pi/5 */
#define KPI5f   (KRADf * PI5f)

// ---------------------------------------------------------------------------
// Cross-lane reductions. Channel-group layouts:
//   16-lane kernels (fwd_b0, force): group = 16 lanes (one channel each)
//   8-lane kernels (fwd_b1, bwd_*): group = 8 lanes (channel PAIR each)
// ---------------------------------------------------------------------------
__device__ __forceinline__ float grp16_sum(float v){
  v += __shfl_xor(v, 1, 64);
  v += __shfl_xor(v, 2, 64);
  v += __shfl_xor(v, 4, 64);
  v += __shfl_xor(v, 8, 64);
  return v;
}
__device__ __forceinline__ float grp8_sum(float v){
  v += __shfl_xor(v, 1, 64);
  v += __shfl_xor(v, 2, 64);
  v += __shfl_xor(v, 4, 64);
  return v;
}
__device__ __forceinline__ float xgrp8_sum(float v){   // across 8 edge-groups
  v += __shfl_xor(v, 8, 64);
  v += __shfl_xor(v, 16, 64);
  v += __shfl_xor(v, 32, 64);
  return v;
}
__device__ __forceinline__ float xgrp_sum(float v){    // across 4 edge-groups
  v += __shfl_xor(v, 16, 64);
  v += __shfl_xor(v, 32, 64);
  return v;
}

// sh from unit vector (8 ops)
__device__ __forceinline__ void sh_from_u(float ux, float uy, float uz,
                                          float* sh1, float* sh2)
{
  sh1[0] = SQRT3f*ux; sh1[1] = SQRT3f*uy; sh1[2] = SQRT3f*uz;
  sh2[0] = SQRT15f*ux*uy;
  sh2[1] = SQRT15f*uy*uz;
  sh2[2] = 0.5f*SQRT5f*(3.f*uz*uz - 1.f);
  sh2[3] = SQRT15f*ux*uz;
  sh2[4] = 0.5f*SQRT15f*(ux*ux - uy*uy);
}

// Chebyshev recurrence from (s1,c1)=sincos(pi*r/5): rad only (fwd_b0)
__device__ __forceinline__ void rad_from_sc(float s1, float c1, float inv_r, float* rad)
{
  float tc = 2.f * c1;
  float sprev = 0.f, s = s1;
  float Ki = KRADf * inv_r;
  #pragma unroll
  for (int k = 0; k < 8; k++) {
    rad[k] = Ki * s;
    float sn = tc*s - sprev; sprev = s; s = sn;
  }
}

// NOTE (r16 post-mortem, carried forward): precomputing rad/draddr into a
// streamed per-edge buffer regressed (prefetch state spilled to scratch,
// +100 MB HBM). Recompute-in-register stays. This round the bwd kernels use
// a MERGED k-loop: w,t,P,Q accumulated in one pass, draddr never
// materialized: gr = inv_r*(KPI5*P - Q), P = sum t_k*(k+1)*cos_k,
// Q = sum t_k*rad_k.

// ---------------------------------------------------------------------------
// Degree histogram (E-parallel)
// ---------------------------------------------------------------------------
__global__ void k_hist(const int* __restrict__ ei, int E,
                       int* __restrict__ deg_row, int* __restrict__ deg_col)
{
  int e = blockIdx.x * blockDim.x + threadIdx.x;
  if (e >= E) return;
  atomicAdd(&deg_row[ei[e]], 1);
  atomicAdd(&deg_col[ei[E + e]], 1);
}

// ---------------------------------------------------------------------------
// Scan-free segment allocation: wave-aggregated atomicAdd on global cursors.
// ---------------------------------------------------------------------------
__global__ void k_alloc(const int* __restrict__ deg_row, const int* __restrict__ deg_col,
                        int* __restrict__ start_row, int* __restrict__ cur_row,
                        int* __restrict__ start_col, int* __restrict__ cur_col,
                        int* __restrict__ cursors, int N)
{
  int idx = blockIdx.x * blockDim.x + threadIdx.x;
  int lane = threadIdx.x & 63;
  #pragma unroll
  for (int which = 0; which < 2; which++) {
    const int* deg = which ? deg_col : deg_row;
    int* start = which ? start_col : start_row;
    int* cur   = which ? cur_col   : cur_row;
    int v = (idx < N) ? deg[idx] : 0;
    int incl = v;
    #pragma unroll
    for (int d = 1; d < 64; d <<= 1) {
      int y = __shfl_up(incl, d, 64);
      if (lane >= d) incl += y;
    }
    int wtot = __shfl(incl, 63, 64);
    int base = 0;
    if (lane == 63) base = atomicAdd(&cursors[which], wtot);
    base = __shfl(base, 63, 64);
    if (idx < N) { int st = base + incl - v; start[idx] = st; cur[idx] = st; }
  }
}

// ---------------------------------------------------------------------------
// Scatter + compact geometry in BOTH CSR orders.
// ---------------------------------------------------------------------------
__global__ void k_scatter_geom(const float* __restrict__ pos, const int* __restrict__ ei, int E,
                               int* __restrict__ cur_row, int* __restrict__ cur_col,
                               float4* __restrict__ uR, float2* __restrict__ scR,
                               float4* __restrict__ uC, float2* __restrict__ scC,
                               int* __restrict__ colR, int* __restrict__ cposR,
                               int* __restrict__ rowC, int* __restrict__ rposC)
{
  int e = blockIdx.x * blockDim.x + threadIdx.x;
  if (e >= E) return;
  int row = ei[e], col = ei[E + e];
  int pr = atomicAdd(&cur_row[row], 1);
  int pc = atomicAdd(&cur_col[col], 1);
  colR[pr] = col; cposR[pr] = pc;
  rowC[pc] = row; rposC[pc] = pr;

  float px = pos[row*3+0] - pos[col*3+0];
  float py = pos[row*3+1] - pos[col*3+1];
  float pz = pos[row*3+2] - pos[col*3+2];
  float r2 = px*px + py*py + pz*pz + 1e-12f;
  float r = sqrtf(r2);
  float inv_r = 1.0f / r;
  float ux = px*inv_r, uy = py*inv_r, uz = pz*inv_r;
  float s1, c1;
  sincosf(r * PI5f, &s1, &c1);
  float4 u4 = make_float4(ux, uy, uz, inv_r);
  float2 sc = make_float2(s1, c1);
  uR[pr] = u4; scR[pr] = sc;
  uC[pc] = u4; scC[pc] = sc;
}

// ---------------------------------------------------------------------------
// h0_init[n,:] = emb[z[n],:] @ W_init
// ---------------------------------------------------------------------------
__global__ void k_node_init(const float* __restrict__ emb, const int* __restrict__ z,
                            const float* __restrict__ W_init, float* __restrict__ h0, int N)
{
  __shared__ float sW[256];
  if (threadIdx.x < 256) sW[threadIdx.x] = W_init[threadIdx.x];
  __syncthreads();
  int n = blockIdx.x * blockDim.x + threadIdx.x;
  if (n >= N) return;
  const float* e = emb + z[n]*16;
  float ev[16];
  #pragma unroll
  for (int k = 0; k < 16; k++) ev[k] = e[k];
  #pragma unroll
  for (int c = 0; c < 16; c++) {
    float s = 0.f;
    #pragma unroll
    for (int k = 0; k < 16; k++) s += ev[k] * sW[k*16+c];
    h0[n*16+c] = s;
  }
}

// ---------------------------------------------------------------------------
// Forward block 0 — persistent wave per node (4 groups x 16 channels).
// Kept 16-lane: the 2-ch variant's 18-value cross-group epilogue eats the gain.
// ---------------------------------------------------------------------------
__global__ void k_fwd_b0(const float* __restrict__ Wr, const float* __restrict__ br,
                         const float* __restrict__ h0_in,
                         const float4* __restrict__ uR, const float2* __restrict__ scR,
                         const int* __restrict__ colR,
                         const int* __restrict__ start_row, const int* __restrict__ deg_row,
                         float* __restrict__ a0, float* __restrict__ a1, float* __restrict__ a2,
                         int N)
{
  int wid = (blockIdx.x * blockDim.x + threadIdx.x) >> 6;
  int nw  = (gridDim.x * blockDim.x) >> 6;
  int lane = threadIdx.x & 63;
  int g = lane >> 4, c = lane & 15;
  float wr0[8], wr1[8], wr2[8];
  #pragma unroll
  for (int k = 0; k < 8; k++) {
    wr0[k] = Wr[k*80 + c];
    wr1[k] = Wr[k*80 + 16 + c];
    wr2[k] = Wr[k*80 + 32 + c];
  }
  float b0v = br[c], b1v = br[16 + c], b2v = br[32 + c];

  for (int n = wid; n < N; n += nw) {
    float acc0 = 0.f, acc1[3] = {0.f,0.f,0.f}, acc2[5] = {0.f,0.f,0.f,0.f,0.f};

    int i0 = start_row[n] + g, i1 = start_row[n] + deg_row[n];
    float4 Un = {0,0,0,0}; float2 SCn = {0,0};
    float h0n = 0.f;
    if (i0 < i1) {
      Un = uR[i0]; SCn = scR[i0];
      h0n = h0_in[colR[i0]*16 + c];
    }
    for (int i = i0; i < i1; i += 4) {
      float4 U = Un; float2 SC = SCn;
      float h0c = h0n;
      if (i+4 < i1) {
        Un = uR[i+4]; SCn = scR[i+4];
        h0n = h0_in[colR[i+4]*16 + c];
      }
      float rad[8];
      rad_from_sc(SC.x, SC.y, U.w, rad);
      float sh1[3], sh2[5];
      sh_from_u(U.x, U.y, U.z, sh1, sh2);
      float w0 = b0v, w1 = b1v, w2 = b2v;
      #pragma unroll
      for (int k = 0; k < 8; k++) {
        w0 += rad[k]*wr0[k]; w1 += rad[k]*wr1[k]; w2 += rad[k]*wr2[k];
      }
      acc0 += w0*h0c;
      float wh1 = w1*h0c, wh2 = w2*h0c;
      #pragma unroll
      for (int m = 0; m < 3; m++) acc1[m] += wh1*sh1[m];
      #pragma unroll
      for (int m = 0; m < 5; m++) acc2[m] += wh2*sh2[m];
    }
    acc0 = xgrp_sum(acc0);
    #pragma unroll
    for (int m = 0; m < 3; m++) acc1[m] = xgrp_sum(acc1[m]);
    #pragma unroll
    for (int m = 0; m < 5; m++) acc2[m] = xgrp_sum(acc2[m]);
    if (g == 0) {
      a0[n*16 + c] = acc0;
      #pragma unroll
      for (int m = 0; m < 3; m++) a1[n*48 + c*3 + m] = acc1[m];
      #pragma unroll
      for (int m = 0; m < 5; m++) a2[n*80 + c*5 + m] = acc2[m];
    }
  }
}

// ---------------------------------------------------------------------------
// Forward block 1 (last) — persistent wave per node, 8 groups x channel-PAIR.
// Lane cl owns channels (2cl, 2cl+1): all channel loads become float2;
// edge-uniform rad/sh now amortized over 8 edges/wave instead of 4.
// ---------------------------------------------------------------------------
__global__ void k_fwd_b1(const float* __restrict__ Wr, const float* __restrict__ br,
                         const float* __restrict__ h0_in, const float* __restrict__ h1_in,
                         const float* __restrict__ h2_in,
                         const float4* __restrict__ uR, const float2* __restrict__ scR,
                         const int* __restrict__ colR,
                         const int* __restrict__ start_row, const int* __restrict__ deg_row,
                         float* __restrict__ a0, int N)
{
  int wid = (blockIdx.x * blockDim.x + threadIdx.x) >> 6;
  int nw  = (gridDim.x * blockDim.x) >> 6;
  int lane = threadIdx.x & 63;
  int g = lane >> 3, cl = lane & 7;
  const float2* Wr2 = (const float2*)Wr;
  const float2* br2 = (const float2*)br;
  const float2* h0_2 = (const float2*)h0_in;
  const float2* h1_2 = (const float2*)h1_in;
  const float2* h2_2 = (const float2*)h2_in;

  float2 wr0[8], wr3[8], wr4[8];
  #pragma unroll
  for (int k = 0; k < 8; k++) {
    wr0[k] = Wr2[k*40 + cl];
    wr3[k] = Wr2[k*40 + 24 + cl];
    wr4[k] = Wr2[k*40 + 32 + cl];
  }
  float2 b0v = br2[cl], b3v = br2[24 + cl], b4v = br2[32 + cl];

  for (int n = wid; n < N; n += nw) {
    float acc0x = 0.f, acc0y = 0.f;
    int i0 = start_row[n] + g, i1 = start_row[n] + deg_row[n];
    float4 Un = {0,0,0,0}; float2 SCn = {0,0};
    float2 h0n = {0.f,0.f}; int coln = 0;
    if (i0 < i1) {
      coln = colR[i0];
      Un = uR[i0]; SCn = scR[i0];
      h0n = h0_2[coln*8 + cl];
    }
    for (int i = i0; i < i1; i += 8) {
      float4 U = Un; float2 SC = SCn; float2 h0c = h0n; int col = coln;
      if (i+8 < i1) {
        coln = colR[i+8];
        Un = uR[i+8]; SCn = scR[i+8];
        h0n = h0_2[coln*8 + cl];
      }
      // issue h1/h2 pair loads early; k-loop below hides their latency
      float2 A0 = h1_2[col*24 + 3*cl + 0];
      float2 A1 = h1_2[col*24 + 3*cl + 1];
      float2 A2 = h1_2[col*24 + 3*cl + 2];
      float2 B0 = h2_2[col*40 + 5*cl + 0];
      float2 B1 = h2_2[col*40 + 5*cl + 1];
      float2 B2 = h2_2[col*40 + 5*cl + 2];
      float2 B3 = h2_2[col*40 + 5*cl + 3];
      float2 B4 = h2_2[col*40 + 5*cl + 4];

      float inv_r = U.w;
      float Ki = KRADf * inv_r;
      float tc = 2.f * SC.y;
      float sprev = 0.f, s = SC.x;
      float w0x = b0v.x, w0y = b0v.y, w3x = b3v.x, w3y = b3v.y, w4x = b4v.x, w4y = b4v.y;
      #pragma unroll
      for (int k = 0; k < 8; k++) {
        float rad = Ki * s;
        w0x += rad*wr0[k].x; w0y += rad*wr0[k].y;
        w3x += rad*wr3[k].x; w3y += rad*wr3[k].y;
        w4x += rad*wr4[k].x; w4y += rad*wr4[k].y;
        float sn = tc*s - sprev; sprev = s; s = sn;
      }
      float sh1[3], sh2[5];
      sh_from_u(U.x, U.y, U.z, sh1, sh2);
      // channel c0 = 2cl holds {A0.x,A0.y,A1.x}; c1 = 2cl+1 holds {A1.y,A2.x,A2.y}
      float S1x = A0.x*sh1[0] + A0.y*sh1[1] + A1.x*sh1[2];
      float S1y = A1.y*sh1[0] + A2.x*sh1[1] + A2.y*sh1[2];
      float S2x = B0.x*sh2[0] + B0.y*sh2[1] + B1.x*sh2[2] + B1.y*sh2[3] + B2.x*sh2[4];
      float S2y = B2.y*sh2[0] + B3.x*sh2[1] + B3.y*sh2[2] + B4.x*sh2[3] + B4.y*sh2[4];
      acc0x += w0x*h0c.x + w3x*S1x + w4x*S2x;
      acc0y += w0y*h0c.y + w3y*S1y + w4y*S2y;
    }
    acc0x = xgrp8_sum(acc0x);
    acc0y = xgrp8_sum(acc0y);
    if (g == 0) ((float2*)a0)[n*8 + cl] = make_float2(acc0x, acc0y);
  }
}

// ---------------------------------------------------------------------------
// Node update (block 0 only): h_out = h_in + a @ U
// ---------------------------------------------------------------------------
__global__ void k_node_update(const float* __restrict__ h0_in,
                              const float* __restrict__ a0, const float* __restrict__ a1,
                              const float* __restrict__ a2,
                              const float* __restrict__ U,
                              float* __restrict__ h0_out, float* __restrict__ h1_out,
                              float* __restrict__ h2_out, int N)
{
  int idx = blockIdx.x * blockDim.x + threadIdx.x;
  int n = idx >> 4, d = idx & 15;
  if (n >= N) return;
  const float* U0 = U;
  const float* U1 = U + 256;
  const float* U2 = U + 512;
  float s = h0_in[n*16 + d];
  #pragma unroll
  for (int c = 0; c < 16; c++) s += a0[n*16 + c] * U0[c*16 + d];
  h0_out[n*16 + d] = s;
  float v1[3] = {0.f, 0.f, 0.f};
  #pragma unroll
  for (int c = 0; c < 16; c++) {
    float u = U1[c*16 + d];
    #pragma unroll
    for (int m = 0; m < 3; m++) v1[m] += a1[n*48 + c*3 + m] * u;
  }
  #pragma unroll
  for (int m = 0; m < 3; m++) h1_out[n*48 + d*3 + m] = v1[m];
  float v2[5] = {0.f, 0.f, 0.f, 0.f, 0.f};
  #pragma unroll
  for (int c = 0; c < 16; c++) {
    float u = U2[c*16 + d];
    #pragma unroll
    for (int m = 0; m < 5; m++) v2[m] += a2[n*80 + c*5 + m] * u;
  }
  #pragma unroll
  for (int m = 0; m < 5; m++) h2_out[n*80 + d*5 + m] = v2[m];
}

// ---------------------------------------------------------------------------
// Readout fwd + bwd fused (unchanged).
// ---------------------------------------------------------------------------
__global__ void __launch_bounds__(256, 1)
k_readout_bwd(const float* __restrict__ h0s1, const float* __restrict__ a0in,
              const float* __restrict__ W_read,
              const float* __restrict__ W1, const float* __restrict__ b1,
              const float* __restrict__ W2, const float* __restrict__ b2,
              const float* __restrict__ U0b1,
              float* __restrict__ g0, float* __restrict__ ga0,
              float* __restrict__ partials, int N)
{
  __shared__ float sWr[256], sW1[256], sU[256], sb1[16], sW2[16], sb2;
  __shared__ float swave[4];
  {
    int t = threadIdx.x;
    if (t < 256) { sWr[t] = W_read[t]; sW1[t] = W1[t]; sU[t] = U0b1[t]; }
    if (t < 16)  { sb1[t] = b1[t]; sW2[t] = W2[t]; }
    if (t == 0)  sb2 = b2[0];
  }
  __syncthreads();
  int n = blockIdx.x * blockDim.x + threadIdx.x;
  float site = 0.f;
  if (n < N) {
    float h[16], av[16], inv[16], dt[16], g0v[16];
    #pragma unroll
    for (int d = 0; d < 16; d++) av[d] = a0in[n*16 + d];
    #pragma unroll
    for (int d = 0; d < 16; d++) {
      float s = h0s1[n*16 + d];
      #pragma unroll
      for (int cc = 0; cc < 16; cc++) s += av[cc] * sU[cc*16 + d];
      h[d] = s;
    }
    #pragma unroll
    for (int j = 0; j < 16; j++) {
      float s = 0.f;
      #pragma unroll
      for (int d = 0; d < 16; d++) s += h[d] * sWr[d*16 + j];
      inv[j] = s;
    }
    site = sb2;
    #pragma unroll
    for (int c = 0; c < 16; c++) {
      float t = sb1[c];
      #pragma unroll
      for (int j = 0; j < 16; j++) t += inv[j] * sW1[j*16 + c];
      float sg = 1.f / (1.f + expf(-t));
      float w2v = sW2[c];
      site += t * sg * w2v;
      dt[c] = w2v * sg * (1.f + t * (1.f - sg));
    }
    float dinv[16];
    #pragma unroll
    for (int j = 0; j < 16; j++) {
      float s = 0.f;
      #pragma unroll
      for (int c = 0; c < 16; c++) s += dt[c] * sW1[j*16 + c];
      dinv[j] = s;
    }
    #pragma unroll
    for (int d = 0; d < 16; d++) {
      float s = 0.f;
      #pragma unroll
      for (int j = 0; j < 16; j++) s += dinv[j] * sWr[d*16 + j];
      g0v[d] = s;
      g0[n*16 + d] = s;
    }
    #pragma unroll
    for (int c = 0; c < 16; c++) {
      float s = 0.f;
      #pragma unroll
      for (int d = 0; d < 16; d++) s += g0v[d] * sU[c*16 + d];
      ga0[n*16 + c] = s;
    }
  }
  #pragma unroll
  for (int off = 32; off; off >>= 1) site += __shfl_down(site, off, 64);
  int wave = threadIdx.x >> 6;
  if ((threadIdx.x & 63) == 0) swave[wave] = site;
  __syncthreads();
  if (threadIdx.x == 0)
    partials[blockIdx.x] = swave[0] + swave[1] + swave[2] + swave[3];
}

// Sum per-block partials into energy (single tiny block).
__global__ void k_energy(const float* __restrict__ partials, int nb,
                         float* __restrict__ energy)
{
  int t = threadIdx.x;           // 128 threads (2 waves)
  float s = 0.f;
  for (int i = t; i < nb; i += 128) s += partials[i];
  #pragma unroll
  for (int off = 32; off; off >>= 1) s += __shfl_down(s, off, 64);
  __shared__ float sw[2];
  if ((t & 63) == 0) sw[t >> 6] = s;
  __syncthreads();
  if (t == 0) energy[0] = sw[0] + sw[1];
}

// ---------------------------------------------------------------------------
// ga = g @ U^T (full, for block 0 backward)
// ---------------------------------------------------------------------------
__global__ void k_ga(const float* __restrict__ g0, const float* __restrict__ g1,
                     const float* __restrict__ g2, const float* __restrict__ U,
                     float* __restrict__ ga0, float* __restrict__ ga1, float* __restrict__ ga2,
                     int N)
{
  int idx = blockIdx.x * blockDim.x + threadIdx.x;
  int n = idx >> 4, c = idx & 15;
  if (n >= N) return;
  const float* U0 = U;
  const float* U1 = U + 256;
  const float* U2 = U + 512;
  float s = 0.f;
  #pragma unroll
  for (int d = 0; d < 16; d++) s += g0[n*16 + d] * U0[c*16 + d];
  ga0[n*16 + c] = s;
  float v1[3] = {0.f, 0.f, 0.f};
  #pragma unroll
  for (int d = 0; d < 16; d++) {
    float u = U1[c*16 + d];
    #pragma unroll
    for (int m = 0; m < 3; m++) v1[m] += g1[n*48 + d*3 + m] * u;
  }
  #pragma unroll
  for (int m = 0; m < 3; m++) ga1[n*48 + c*3 + m] = v1[m];
  float v2[5] = {0.f, 0.f, 0.f, 0.f, 0.f};
  #pragma unroll
  for (int d = 0; d < 16; d++) {
    float u = U2[c*16 + d];
    #pragma unroll
    for (int m = 0; m < 5; m++) v2[m] += g2[n*80 + d*5 + m] * u;
  }
  #pragma unroll
  for (int m = 0; m < 5; m++) ga2[n*80 + c*5 + m] = v2[m];
}

// ---------------------------------------------------------------------------
// Backward block 1, col-centric — persistent wave per node, 8 x channel-pair.
// Merged k-loop: w/t/P/Q in one pass; gr = inv_r*(KPI5*P - Q).
// ---------------------------------------------------------------------------
__global__ void k_bwd_b1_col(const float* __restrict__ Wr, const float* __restrict__ br,
                             const float* __restrict__ h0_in, const float* __restrict__ h1_in,
                             const float* __restrict__ h2_in,
                             const float* __restrict__ ga0,
                             const float4* __restrict__ uC, const float2* __restrict__ scC,
                             const int* __restrict__ rowC,
                             const int* __restrict__ start_col, const int* __restrict__ deg_col,
                             float* __restrict__ g0, float* __restrict__ g1, float* __restrict__ g2,
                             float* __restrict__ dv_col, int N)
{
  int wid = (blockIdx.x * blockDim.x + threadIdx.x) >> 6;
  int nw  = (gridDim.x * blockDim.x) >> 6;
  int lane = threadIdx.x & 63;
  int g = lane >> 3, cl = lane & 7;
  const float2* Wr2 = (const float2*)Wr;
  const float2* br2 = (const float2*)br;
  const float2* h0_2 = (const float2*)h0_in;
  const float2* h1_2 = (const float2*)h1_in;
  const float2* h2_2 = (const float2*)h2_in;
  const float2* ga0_2 = (const float2*)ga0;

  float2 wr0[8], wr3[8], wr4[8];
  #pragma unroll
  for (int k = 0; k < 8; k++) {
    wr0[k] = Wr2[k*40 + cl];
    wr3[k] = Wr2[k*40 + 24 + cl];
    wr4[k] = Wr2[k*40 + 32 + cl];
  }
  float2 b0v = br2[cl], b3v = br2[24 + cl], b4v = br2[32 + cl];

  for (int n = wid; n < N; n += nw) {
    float2 h0c = h0_2[n*8 + cl];
    float2 A0 = h1_2[n*24 + 3*cl + 0];
    float2 A1 = h1_2[n*24 + 3*cl + 1];
    float2 A2 = h1_2[n*24 + 3*cl + 2];
    float h1a[3] = {A0.x, A0.y, A1.x};
    float h1b[3] = {A1.y, A2.x, A2.y};
    float2 B0 = h2_2[n*40 + 5*cl + 0];
    float2 B1 = h2_2[n*40 + 5*cl + 1];
    float2 B2 = h2_2[n*40 + 5*cl + 2];
    float2 B3 = h2_2[n*40 + 5*cl + 3];
    float2 B4 = h2_2[n*40 + 5*cl + 4];
    float h2a[5] = {B0.x, B0.y, B1.x, B1.y, B2.x};
    float h2b[5] = {B2.y, B3.x, B3.y, B4.x, B4.y};

    float accg0x = 0.f, accg0y = 0.f;
    float accg1a[3] = {0.f,0.f,0.f}, accg1b[3] = {0.f,0.f,0.f};
    float accg2a[5] = {0.f,0.f,0.f,0.f,0.f}, accg2b[5] = {0.f,0.f,0.f,0.f,0.f};

    int i0 = start_col[n] + g, i1 = start_col[n] + deg_col[n];
    float4 Un = {0,0,0,0}; float2 SCn = {0,0};
    float2 dm0n = {0.f,0.f};
    if (i0 < i1) {
      Un = uC[i0]; SCn = scC[i0];
      dm0n = ga0_2[rowC[i0]*8 + cl];
    }
    for (int i = i0; i < i1; i += 8) {
      float4 U = Un; float2 SC = SCn; float2 dm0 = dm0n;
      if (i + 8 < i1) {
        Un = uC[i+8]; SCn = scC[i+8];
        dm0n = ga0_2[rowC[i+8]*8 + cl];
      }
      float sh1[3], sh2[5];
      sh_from_u(U.x, U.y, U.z, sh1, sh2);
      float S1x = h1a[0]*sh1[0] + h1a[1]*sh1[1] + h1a[2]*sh1[2];
      float S1y = h1b[0]*sh1[0] + h1b[1]*sh1[1] + h1b[2]*sh1[2];
      float S2x = h2a[0]*sh2[0] + h2a[1]*sh2[1] + h2a[2]*sh2[2] + h2a[3]*sh2[3] + h2a[4]*sh2[4];
      float S2y = h2b[0]*sh2[0] + h2b[1]*sh2[1] + h2b[2]*sh2[2] + h2b[3]*sh2[3] + h2b[4]*sh2[4];
      float dw0x = dm0.x*h0c.x, dw0y = dm0.y*h0c.y;
      float dw3x = dm0.x*S1x,   dw3y = dm0.y*S1y;
      float dw4x = dm0.x*S2x,   dw4y = dm0.y*S2y;

      float inv_r = U.w;
      float Ki = KRADf * inv_r;
      float tc = 2.f * SC.y;
      float sprev = 0.f, s = SC.x, cprev = 1.f, cc = SC.y;
      float w0x = b0v.x, w0y = b0v.y, w3x = b3v.x, w3y = b3v.y, w4x = b4v.x, w4y = b4v.y;
      float P = 0.f, Q = 0.f;
      #pragma unroll
      for (int k = 0; k < 8; k++) {
        float rad = Ki * s;
        w0x += rad*wr0[k].x; w0y += rad*wr0[k].y;
        w3x += rad*wr3[k].x; w3y += rad*wr3[k].y;
        w4x += rad*wr4[k].x; w4y += rad*wr4[k].y;
        float t = dw0x*wr0[k].x + dw0y*wr0[k].y
                + dw3x*wr3[k].x + dw3y*wr3[k].y
                + dw4x*wr4[k].x + dw4y*wr4[k].y;
        P += (t*cc) * (float)(k+1);
        Q += t*rad;
        float sn = tc*s - sprev; sprev = s; s = sn;
        float cn = tc*cc - cprev; cprev = cc; cc = cn;
      }
      accg0x += dm0.x*w0x; accg0y += dm0.y*w0y;
      float t3x = dm0.x*w3x, t3y = dm0.y*w3y;
      float t4x = dm0.x*w4x, t4y = dm0.y*w4y;
      #pragma unroll
      for (int m = 0; m < 3; m++) { accg1a[m] += t3x*sh1[m]; accg1b[m] += t3y*sh1[m]; }
      #pragma unroll
      for (int m = 0; m < 5; m++) { accg2a[m] += t4x*sh2[m]; accg2b[m] += t4y*sh2[m]; }

      float q1x = t3x*h1a[0] + t3y*h1b[0];
      float q1y = t3x*h1a[1] + t3y*h1b[1];
      float q1z = t3x*h1a[2] + t3y*h1b[2];
      float q0 = t4x*h2a[0] + t4y*h2b[0];
      float q1 = t4x*h2a[1] + t4y*h2b[1];
      float q2 = t4x*h2a[2] + t4y*h2b[2];
      float q3 = t4x*h2a[3] + t4y*h2b[3];
      float q4 = t4x*h2a[4] + t4y*h2b[4];

      float gr = (KPI5f*P - Q) * inv_r;
      float gux = SQRT3f*q1x + SQRT15f*(U.y*q0 + U.z*q3 + U.x*q4);
      float guy = SQRT3f*q1y + SQRT15f*(U.x*q0 + U.z*q1 - U.y*q4);
      float guz = SQRT3f*q1z + SQRT15f*U.y*q1 + 3.f*SQRT5f*U.z*q2 + SQRT15f*U.x*q3;

      gr  = grp8_sum(gr);
      gux = grp8_sum(gux);
      guy = grp8_sum(guy);
      guz = grp8_sum(guz);

      if (cl == 0) {
        float gdotu = gux*U.x + guy*U.y + guz*U.z;
        dv_col[i*3+0] = gr*U.x + (gux - gdotu*U.x)*inv_r;
        dv_col[i*3+1] = gr*U.y + (guy - gdotu*U.y)*inv_r;
        dv_col[i*3+2] = gr*U.z + (guz - gdotu*U.z)*inv_r;
      }
    }
    accg0x = xgrp8_sum(accg0x); accg0y = xgrp8_sum(accg0y);
    #pragma unroll
    for (int m = 0; m < 3; m++) { accg1a[m] = xgrp8_sum(accg1a[m]); accg1b[m] = xgrp8_sum(accg1b[m]); }
    #pragma unroll
    for (int m = 0; m < 5; m++) { accg2a[m] = xgrp8_sum(accg2a[m]); accg2b[m] = xgrp8_sum(accg2b[m]); }
    if (g == 0) {
      float2* g0_2 = (float2*)g0;
      float2 old = g0_2[n*8 + cl];
      g0_2[n*8 + cl] = make_float2(old.x + accg0x, old.y + accg0y);
      float2* g1_2 = (float2*)g1;
      g1_2[n*24 + 3*cl + 0] = make_float2(accg1a[0], accg1a[1]);
      g1_2[n*24 + 3*cl + 1] = make_float2(accg1a[2], accg1b[0]);
      g1_2[n*24 + 3*cl + 2] = make_float2(accg1b[1], accg1b[2]);
      float2* g2_2 = (float2*)g2;
      g2_2[n*40 + 5*cl + 0] = make_float2(accg2a[0], accg2a[1]);
      g2_2[n*40 + 5*cl + 1] = make_float2(accg2a[2], accg2a[3]);
      g2_2[n*40 + 5*cl + 2] = make_float2(accg2a[4], accg2b[0]);
      g2_2[n*40 + 5*cl + 3] = make_float2(accg2b[1], accg2b[2]);
      g2_2[n*40 + 5*cl + 4] = make_float2(accg2b[3], accg2b[4]);
    }
  }
}

// ---------------------------------------------------------------------------
// Backward block 0, row-centric — persistent wave per node, 8 x channel-pair.
// No node-level gradient accumulation (only dv per edge) -> no epilogue.
// ---------------------------------------------------------------------------
__global__ void k_bwd_b0_row(const float* __restrict__ Wr, const float* __restrict__ br,
                             const float* __restrict__ h0_in,
                             const float* __restrict__ ga0, const float* __restrict__ ga1,
                             const float* __restrict__ ga2,
                             const float4* __restrict__ uR, const float2* __restrict__ scR,
                             const int* __restrict__ colR,
                             const int* __restrict__ start_row, const int* __restrict__ deg_row,
                             float* __restrict__ dv_row, int N)
{
  int wid = (blockIdx.x * blockDim.x + threadIdx.x) >> 6;
  int nw  = (gridDim.x * blockDim.x) >> 6;
  int lane = threadIdx.x & 63;
  int g = lane >> 3, cl = lane & 7;
  const float2* Wr2 = (const float2*)Wr;
  const float2* br2 = (const float2*)br;
  const float2* h0_2 = (const float2*)h0_in;
  const float2* ga0_2 = (const float2*)ga0;
  const float2* ga1_2 = (const float2*)ga1;
  const float2* ga2_2 = (const float2*)ga2;

  float2 wr0[8], wr1[8], wr2[8];
  #pragma unroll
  for (int k = 0; k < 8; k++) {
    wr0[k] = Wr2[k*40 + cl];
    wr1[k] = Wr2[k*40 + 8 + cl];
    wr2[k] = Wr2[k*40 + 16 + cl];
  }
  float2 b1v = br2[8 + cl], b2v = br2[16 + cl];

  for (int n = wid; n < N; n += nw) {
    float2 dm0 = ga0_2[n*8 + cl];
    float2 A0 = ga1_2[n*24 + 3*cl + 0];
    float2 A1 = ga1_2[n*24 + 3*cl + 1];
    float2 A2 = ga1_2[n*24 + 3*cl + 2];
    float dm1a[3] = {A0.x, A0.y, A1.x};
    float dm1b[3] = {A1.y, A2.x, A2.y};
    float2 B0 = ga2_2[n*40 + 5*cl + 0];
    float2 B1 = ga2_2[n*40 + 5*cl + 1];
    float2 B2 = ga2_2[n*40 + 5*cl + 2];
    float2 B3 = ga2_2[n*40 + 5*cl + 3];
    float2 B4 = ga2_2[n*40 + 5*cl + 4];
    float dm2a[5] = {B0.x, B0.y, B1.x, B1.y, B2.x};
    float dm2b[5] = {B2.y, B3.x, B3.y, B4.x, B4.y};

    int i0 = start_row[n] + g, i1 = start_row[n] + deg_row[n];
    float4 Un = {0,0,0,0}; float2 SCn = {0,0};
    float2 h0n = {0.f,0.f};
    if (i0 < i1) {
      Un = uR[i0]; SCn = scR[i0];
      h0n = h0_2[colR[i0]*8 + cl];
    }
    for (int i = i0; i < i1; i += 8) {
      float4 U = Un; float2 SC = SCn; float2 h0c = h0n;
      if (i + 8 < i1) {
        Un = uR[i+8]; SCn = scR[i+8];
        h0n = h0_2[colR[i+8]*8 + cl];
      }
      float sh1[3], sh2[5];
      sh_from_u(U.x, U.y, U.z, sh1, sh2);
      float T1x = dm1a[0]*sh1[0] + dm1a[1]*sh1[1] + dm1a[2]*sh1[2];
      float T1y = dm1b[0]*sh1[0] + dm1b[1]*sh1[1] + dm1b[2]*sh1[2];
      float T2x = dm2a[0]*sh2[0] + dm2a[1]*sh2[1] + dm2a[2]*sh2[2] + dm2a[3]*sh2[3] + dm2a[4]*sh2[4];
      float T2y = dm2b[0]*sh2[0] + dm2b[1]*sh2[1] + dm2b[2]*sh2[2] + dm2b[3]*sh2[3] + dm2b[4]*sh2[4];
      float dw0x = dm0.x*h0c.x, dw0y = dm0.y*h0c.y;
      float dw1x = h0c.x*T1x,  dw1y = h0c.y*T1y;
      float dw2x = h0c.x*T2x,  dw2y = h0c.y*T2y;

      float inv_r = U.w;
      float Ki = KRADf * inv_r;
      float tc = 2.f * SC.y;
      float sprev = 0.f, s = SC.x, cprev = 1.f, cc = SC.y;
      float w1x = b1v.x, w1y = b1v.y, w2x = b2v.x, w2y = b2v.y;
      float P = 0.f, Q = 0.f;
      #pragma unroll
      for (int k = 0; k < 8; k++) {
        float rad = Ki * s;
        w1x += rad*wr1[k].x; w1y += rad*wr1[k].y;
        w2x += rad*wr2[k].x; w2y += rad*wr2[k].y;
        float t = dw0x*wr0[k].x + dw0y*wr0[k].y
                + dw1x*wr1[k].x + dw1y*wr1[k].y
                + dw2x*wr2[k].x + dw2y*wr2[k].y;
        P += (t*cc) * (float)(k+1);
        Q += t*rad;
        float sn = tc*s - sprev; sprev = s; s = sn;
        float cn = tc*cc - cprev; cprev = cc; cc = cn;
      }
      float w1hx = w1x*h0c.x, w1hy = w1y*h0c.y;
      float w2hx = w2x*h0c.x, w2hy = w2y*h0c.y;
      float q1x = dm1a[0]*w1hx + dm1b[0]*w1hy;
      float q1y = dm1a[1]*w1hx + dm1b[1]*w1hy;
      float q1z = dm1a[2]*w1hx + dm1b[2]*w1hy;
      float q0 = dm2a[0]*w2hx + dm2b[0]*w2hy;
      float q1 = dm2a[1]*w2hx + dm2b[1]*w2hy;
      float q2 = dm2a[2]*w2hx + dm2b[2]*w2hy;
      float q3 = dm2a[3]*w2hx + dm2b[3]*w2hy;
      float q4 = dm2a[4]*w2hx + dm2b[4]*w2hy;

      float gr = (KPI5f*P - Q) * inv_r;
      float gux = SQRT3f*q1x + SQRT15f*(U.y*q0 + U.z*q3 + U.x*q4);
      float guy = SQRT3f*q1y + SQRT15f*(U.x*q0 + U.z*q1 - U.y*q4);
      float guz = SQRT3f*q1z + SQRT15f*U.y*q1 + 3.f*SQRT5f*U.z*q2 + SQRT15f*U.x*q3;

      gr  = grp8_sum(gr);
      gux = grp8_sum(gux);
      guy = grp8_sum(guy);
      guz = grp8_sum(guz);

      if (cl == 0) {
        float gdotu = gux*U.x + guy*U.y + guz*U.z;
        dv_row[i*3+0] = gr*U.x + (gux - gdotu*U.x)*inv_r;
        dv_row[i*3+1] = gr*U.y + (guy - gdotu*U.y)*inv_r;
        dv_row[i*3+2] = gr*U.z + (guz - gdotu*U.z)*inv_r;
      }
    }
  }
}

// ---------------------------------------------------------------------------
// Force assembly: 16 lanes per node (was 1 thread/node = 117 blocks, pure
// latency exposure). dv_e = dv_col[colpos(e)] + dv_row[rowpos(e)].
// ---------------------------------------------------------------------------
__global__ void k_force(const int* __restrict__ start_row, const int* __restrict__ deg_row,
                        const int* __restrict__ cposR,
                        const int* __restrict__ start_col, const int* __restrict__ deg_col,
                        const int* __restrict__ rposC,
                        const float* __restrict__ dv_col, const float* __restrict__ dv_row,
                        float* __restrict__ force, int N)
{
  int idx = blockIdx.x * blockDim.x + threadIdx.x;
  int n = idx >> 4, l = idx & 15;
  if (n >= N) return;
  float fx = 0.f, fy = 0.f, fz = 0.f;
  int c0 = start_col[n], c1 = c0 + deg_col[n];
  for (int i = c0 + l; i < c1; i += 16) {
    int rp = rposC[i];
    fx += dv_col[i*3+0] + dv_row[rp*3+0];
    fy += dv_col[i*3+1] + dv_row[rp*3+1];
    fz += dv_col[i*3+2] + dv_row[rp*3+2];
  }
  int r0 = start_row[n], r1 = r0 + deg_row[n];
  for (int i = r0 + l; i < r1; i += 16) {
    int cp = cposR[i];
    fx -= dv_row[i*3+0] + dv_col[cp*3+0];
    fy -= dv_row[i*3+1] + dv_col[cp*3+1];
    fz -= dv_row[i*3+2] + dv_col[cp*3+2];
  }
  fx = grp16_sum(fx); fy = grp16_sum(fy); fz = grp16_sum(fz);
  if (l == 0) {
    force[n*3+0] = fx; force[n*3+1] = fy; force[n*3+2] = fz;
  }
}

// ---------------------------------------------------------------------------
extern "C" void kernel_launch(void* const* d_in, const int* in_sizes, int n_in,
                              void* d_out, int out_size, void* d_ws, size_t ws_size,
                              hipStream_t stream)
{
  const float* pos    = (const float*)d_in[0];
  const int*   z      = (const int*)  d_in[1];
  const int*   ei     = (const int*)  d_in[2];
  const float* emb    = (const float*)d_in[3];
  const float* W_init = (const float*)d_in[4];
  const float* Wr     = (const float*)d_in[5];   // (2, 8, 80)
  const float* br     = (const float*)d_in[6];   // (2, 80)
  const float* W_out  = (const float*)d_in[7];   // (2, 3, 16, 16)
  const float* W_read = (const float*)d_in[8];
  const float* W1     = (const float*)d_in[9];
  const float* b1     = (const float*)d_in[10];
  const float* W2     = (const float*)d_in[11];
  const float* b2     = (const float*)d_in[12];

  const int N = in_sizes[0] / 3;
  const int E = in_sizes[2] / 2;

  const int BLK = 256;
  const int NB_READOUT = cdiv(N, BLK);
  // Persistent grid for wave-per-node kernels: 2048 blocks = 8192 waves;
  // ~3.7 nodes/wave amortizes the Wr/br register prologue, and with the
  // 2-ch kernels at ~4 waves/SIMD residency there are ~2 scheduling rounds
  // (backfill smoothing of degree imbalance).
  const int PBLK = (N < 8192*1) ? cdiv(N, 4) : 2048;

  float* f = (float*)d_ws;
  float4* uR  = (float4*)f; f += (size_t)E*4;
  float4* uC  = (float4*)f; f += (size_t)E*4;
  float2* scR = (float2*)f; f += (size_t)E*2;
  float2* scC = (float2*)f; f += (size_t)E*2;
  float* h0_s0 = f; f += (size_t)N*16;
  float* h0_s1 = f; f += (size_t)N*16;
  float* h1_s1 = f; f += (size_t)N*48;
  float* h2_s1 = f; f += (size_t)N*80;
  float* a0    = f; f += (size_t)N*16;   // block-0 agg, then block-1 agg, then ga0_b0
  float* a1    = f; f += (size_t)N*48;   //                                 ga1_b0
  float* a2    = f; f += (size_t)N*80;   //                                 ga2_b0
  float* ga0b1 = f; f += (size_t)N*16;   // readout's ga0 (dE/da0 block 1)
  float* g0    = f; f += (size_t)N*16;
  float* g1    = f; f += (size_t)N*48;
  float* g2    = f; f += (size_t)N*80;
  float* dv_c  = f; f += (size_t)E*3;    // dv from bwd b1, col order
  float* dv_r  = f; f += (size_t)E*3;    // dv from bwd b0, row order
  float* partials = f; f += (size_t)NB_READOUT;
  int* ip = (int*)f;
  int* cursors   = ip; ip += 2;          // cursors+deg contiguous -> one memset
  int* deg_row   = ip; ip += N;
  int* deg_col   = ip; ip += N;
  int* start_row = ip; ip += N;
  int* start_col = ip; ip += N;
  int* cur_row   = ip; ip += N;
  int* cur_col   = ip; ip += N;
  int* colR      = ip; ip += E;
  int* cposR     = ip; ip += E;
  int* rowC      = ip; ip += E;
  int* rposC     = ip; ip += E;

  float* out    = (float*)d_out;
  float* energy = out;
  float* force  = out + 1;

  (void)hipMemsetAsync(cursors, 0, (size_t)(2 + 2*N) * sizeof(int), stream);

  // ---- CSR build (scan-free) + compact geometry in both orders ----
  k_hist<<<cdiv(E, BLK), BLK, 0, stream>>>(ei, E, deg_row, deg_col);
  k_alloc<<<cdiv(N, BLK), BLK, 0, stream>>>(deg_row, deg_col, start_row, cur_row,
                                            start_col, cur_col, cursors, N);
  k_scatter_geom<<<cdiv(E, BLK), BLK, 0, stream>>>(pos, ei, E, cur_row, cur_col,
                                                   uR, scR, uC, scC,
                                                   colR, cposR, rowC, rposC);

  k_node_init<<<cdiv(N, BLK), BLK, 0, stream>>>(emb, z, W_init, h0_s0, N);

  // ---- forward block 0 ----
  k_fwd_b0<<<PBLK, BLK, 0, stream>>>(Wr, br, h0_s0, uR, scR, colR,
                                     start_row, deg_row, a0, a1, a2, N);
  k_node_update<<<cdiv(N*16, BLK), BLK, 0, stream>>>(h0_s0, a0, a1, a2,
                                                     W_out, h0_s1, h1_s1, h2_s1, N);

  // ---- forward block 1 (h0_s2 folded into readout) ----
  k_fwd_b1<<<PBLK, BLK, 0, stream>>>(Wr + 640, br + 80,
                                     h0_s1, h1_s1, h2_s1, uR, scR, colR,
                                     start_row, deg_row, a0, N);

  // ---- readout fwd + bwd (includes block-1 h0 update; emits g0, ga0b1) ----
  k_readout_bwd<<<NB_READOUT, BLK, 0, stream>>>(h0_s1, a0, W_read, W1, b1, W2, b2,
                                                W_out + 768, g0, ga0b1, partials, N);
  k_energy<<<1, 128, 0, stream>>>(partials, NB_READOUT, energy);

  // ---- backward block 1 ----
  k_bwd_b1_col<<<PBLK, BLK, 0, stream>>>(Wr + 640, br + 80,
                                         h0_s1, h1_s1, h2_s1, ga0b1,
                                         uC, scC, rowC, start_col, deg_col,
                                         g0, g1, g2, dv_c, N);

  // ---- backward block 0 ----
  k_ga<<<cdiv(N*16, BLK), BLK, 0, stream>>>(g0, g1, g2, W_out, a0, a1, a2, N);
  k_bwd_b0_row<<<PBLK, BLK, 0, stream>>>(Wr, br, h0_s0,
                                         a0, a1, a2, uR, scR, colR,
                                         start_row, deg_row, dv_r, N);

  // ---- force assembly ----
  k_force<<<cdiv(N*16, BLK), BLK, 0, stream>>>(start_row, deg_row, cposR,
                                               start_col, deg_col, rposC,
                                               dv_c, dv_r, force, N);
}

// Round 2
// 493.160 us; speedup vs baseline: 1.8232x; 1.8232x over previous
//
#include <hip/hip_runtime.h>
#include <math.h>

#ifndef M_PI
#define M_PI 3.14159265358979323846
#endif

static inline int cdiv(int a, int b){ return (a + b - 1) / b; }

#define SQRT3f  1.7320508075688772f
#define SQRT5f  2.23606797749979f
#define SQRT15f 3.872983346207417f
#define KRADf   0.6324555320336759f      /* sqrt(2/R_MAX), R_MAX=5 */
#define PI5f    0.6283185307179586f      /* pi/5 */
#define KPI5f   (KRADf * PI5f)

// ---------------------------------------------------------------------------
// R1 post-mortem: the 2-ch kernels demand ~140 VGPRs; without launch_bounds
// the allocator clamped to the 64-VGPR tier and SPILLED (FETCH 929MB, WRITE
// 735MB of scratch traffic, VALUBusy 68->10%). Fix: __launch_bounds__(256,2)
// -> VGPR cap 256, no spill, ~3 waves/SIMD from actual demand.
// ---------------------------------------------------------------------------

// Cross-lane reductions. Channel-group layouts:
//   16-lane kernels (fwd_b0, force): group = 16 lanes (one channel each)
//   8-lane kernels (fwd_b1, bwd_*): group = 8 lanes (channel PAIR each)
__device__ __forceinline__ float grp16_sum(float v){
  v += __shfl_xor(v, 1, 64);
  v += __shfl_xor(v, 2, 64);
  v += __shfl_xor(v, 4, 64);
  v += __shfl_xor(v, 8, 64);
  return v;
}
__device__ __forceinline__ float grp8_sum(float v){
  v += __shfl_xor(v, 1, 64);
  v += __shfl_xor(v, 2, 64);
  v += __shfl_xor(v, 4, 64);
  return v;
}
__device__ __forceinline__ float xgrp8_sum(float v){   // across 8 edge-groups
  v += __shfl_xor(v, 8, 64);
  v += __shfl_xor(v, 16, 64);
  v += __shfl_xor(v, 32, 64);
  return v;
}
__device__ __forceinline__ float xgrp_sum(float v){    // across 4 edge-groups
  v += __shfl_xor(v, 16, 64);
  v += __shfl_xor(v, 32, 64);
  return v;
}

// sh from unit vector (8 ops)
__device__ __forceinline__ void sh_from_u(float ux, float uy, float uz,
                                          float* sh1, float* sh2)
{
  sh1[0] = SQRT3f*ux; sh1[1] = SQRT3f*uy; sh1[2] = SQRT3f*uz;
  sh2[0] = SQRT15f*ux*uy;
  sh2[1] = SQRT15f*uy*uz;
  sh2[2] = 0.5f*SQRT5f*(3.f*uz*uz - 1.f);
  sh2[3] = SQRT15f*ux*uz;
  sh2[4] = 0.5f*SQRT15f*(ux*ux - uy*uy);
}

// Chebyshev recurrence from (s1,c1)=sincos(pi*r/5): rad only (fwd_b0)
__device__ __forceinline__ void rad_from_sc(float s1, float c1, float inv_r, float* rad)
{
  float tc = 2.f * c1;
  float sprev = 0.f, s = s1;
  float Ki = KRADf * inv_r;
  #pragma unroll
  for (int k = 0; k < 8; k++) {
    rad[k] = Ki * s;
    float sn = tc*s - sprev; sprev = s; s = sn;
  }
}

// NOTE (r16 post-mortem, carried forward): precomputing rad/draddr into a
// streamed per-edge buffer regressed (prefetch state spilled to scratch,
// +100 MB HBM). Recompute-in-register stays. Bwd kernels use a MERGED
// k-loop: w,t,P,Q accumulated in one pass, draddr never materialized:
// gr = inv_r*(KPI5*P - Q), P = sum t_k*(k+1)*cos_k, Q = sum t_k*rad_k.

// ---------------------------------------------------------------------------
// Degree histogram (E-parallel)
// ---------------------------------------------------------------------------
__global__ void k_hist(const int* __restrict__ ei, int E,
                       int* __restrict__ deg_row, int* __restrict__ deg_col)
{
  int e = blockIdx.x * blockDim.x + threadIdx.x;
  if (e >= E) return;
  atomicAdd(&deg_row[ei[e]], 1);
  atomicAdd(&deg_col[ei[E + e]], 1);
}

// ---------------------------------------------------------------------------
// Scan-free segment allocation: wave-aggregated atomicAdd on global cursors.
// ---------------------------------------------------------------------------
__global__ void k_alloc(const int* __restrict__ deg_row, const int* __restrict__ deg_col,
                        int* __restrict__ start_row, int* __restrict__ cur_row,
                        int* __restrict__ start_col, int* __restrict__ cur_col,
                        int* __restrict__ cursors, int N)
{
  int idx = blockIdx.x * blockDim.x + threadIdx.x;
  int lane = threadIdx.x & 63;
  #pragma unroll
  for (int which = 0; which < 2; which++) {
    const int* deg = which ? deg_col : deg_row;
    int* start = which ? start_col : start_row;
    int* cur   = which ? cur_col   : cur_row;
    int v = (idx < N) ? deg[idx] : 0;
    int incl = v;
    #pragma unroll
    for (int d = 1; d < 64; d <<= 1) {
      int y = __shfl_up(incl, d, 64);
      if (lane >= d) incl += y;
    }
    int wtot = __shfl(incl, 63, 64);
    int base = 0;
    if (lane == 63) base = atomicAdd(&cursors[which], wtot);
    base = __shfl(base, 63, 64);
    if (idx < N) { int st = base + incl - v; start[idx] = st; cur[idx] = st; }
  }
}

// ---------------------------------------------------------------------------
// Scatter + compact geometry in BOTH CSR orders.
// ---------------------------------------------------------------------------
__global__ void k_scatter_geom(const float* __restrict__ pos, const int* __restrict__ ei, int E,
                               int* __restrict__ cur_row, int* __restrict__ cur_col,
                               float4* __restrict__ uR, float2* __restrict__ scR,
                               float4* __restrict__ uC, float2* __restrict__ scC,
                               int* __restrict__ colR, int* __restrict__ cposR,
                               int* __restrict__ rowC, int* __restrict__ rposC)
{
  int e = blockIdx.x * blockDim.x + threadIdx.x;
  if (e >= E) return;
  int row = ei[e], col = ei[E + e];
  int pr = atomicAdd(&cur_row[row], 1);
  int pc = atomicAdd(&cur_col[col], 1);
  colR[pr] = col; cposR[pr] = pc;
  rowC[pc] = row; rposC[pc] = pr;

  float px = pos[row*3+0] - pos[col*3+0];
  float py = pos[row*3+1] - pos[col*3+1];
  float pz = pos[row*3+2] - pos[col*3+2];
  float r2 = px*px + py*py + pz*pz + 1e-12f;
  float r = sqrtf(r2);
  float inv_r = 1.0f / r;
  float ux = px*inv_r, uy = py*inv_r, uz = pz*inv_r;
  float s1, c1;
  sincosf(r * PI5f, &s1, &c1);
  float4 u4 = make_float4(ux, uy, uz, inv_r);
  float2 sc = make_float2(s1, c1);
  uR[pr] = u4; scR[pr] = sc;
  uC[pc] = u4; scC[pc] = sc;
}

// ---------------------------------------------------------------------------
// h0_init[n,:] = emb[z[n],:] @ W_init
// ---------------------------------------------------------------------------
__global__ void k_node_init(const float* __restrict__ emb, const int* __restrict__ z,
                            const float* __restrict__ W_init, float* __restrict__ h0, int N)
{
  __shared__ float sW[256];
  if (threadIdx.x < 256) sW[threadIdx.x] = W_init[threadIdx.x];
  __syncthreads();
  int n = blockIdx.x * blockDim.x + threadIdx.x;
  if (n >= N) return;
  const float* e = emb + z[n]*16;
  float ev[16];
  #pragma unroll
  for (int k = 0; k < 16; k++) ev[k] = e[k];
  #pragma unroll
  for (int c = 0; c < 16; c++) {
    float s = 0.f;
    #pragma unroll
    for (int k = 0; k < 16; k++) s += ev[k] * sW[k*16+c];
    h0[n*16+c] = s;
  }
}

// ---------------------------------------------------------------------------
// Forward block 0 — persistent wave per node (4 groups x 16 channels).
// ---------------------------------------------------------------------------
__global__ void __launch_bounds__(256, 2)
k_fwd_b0(const float* __restrict__ Wr, const float* __restrict__ br,
         const float* __restrict__ h0_in,
         const float4* __restrict__ uR, const float2* __restrict__ scR,
         const int* __restrict__ colR,
         const int* __restrict__ start_row, const int* __restrict__ deg_row,
         float* __restrict__ a0, float* __restrict__ a1, float* __restrict__ a2,
         int N)
{
  int wid = (blockIdx.x * blockDim.x + threadIdx.x) >> 6;
  int nw  = (gridDim.x * blockDim.x) >> 6;
  int lane = threadIdx.x & 63;
  int g = lane >> 4, c = lane & 15;
  float wr0[8], wr1[8], wr2[8];
  #pragma unroll
  for (int k = 0; k < 8; k++) {
    wr0[k] = Wr[k*80 + c];
    wr1[k] = Wr[k*80 + 16 + c];
    wr2[k] = Wr[k*80 + 32 + c];
  }
  float b0v = br[c], b1v = br[16 + c], b2v = br[32 + c];

  for (int n = wid; n < N; n += nw) {
    float acc0 = 0.f, acc1[3] = {0.f,0.f,0.f}, acc2[5] = {0.f,0.f,0.f,0.f,0.f};

    int i0 = start_row[n] + g, i1 = start_row[n] + deg_row[n];
    float4 Un = {0,0,0,0}; float2 SCn = {0,0};
    float h0n = 0.f;
    if (i0 < i1) {
      Un = uR[i0]; SCn = scR[i0];
      h0n = h0_in[colR[i0]*16 + c];
    }
    for (int i = i0; i < i1; i += 4) {
      float4 U = Un; float2 SC = SCn;
      float h0c = h0n;
      if (i+4 < i1) {
        Un = uR[i+4]; SCn = scR[i+4];
        h0n = h0_in[colR[i+4]*16 + c];
      }
      float rad[8];
      rad_from_sc(SC.x, SC.y, U.w, rad);
      float sh1[3], sh2[5];
      sh_from_u(U.x, U.y, U.z, sh1, sh2);
      float w0 = b0v, w1 = b1v, w2 = b2v;
      #pragma unroll
      for (int k = 0; k < 8; k++) {
        w0 += rad[k]*wr0[k]; w1 += rad[k]*wr1[k]; w2 += rad[k]*wr2[k];
      }
      acc0 += w0*h0c;
      float wh1 = w1*h0c, wh2 = w2*h0c;
      #pragma unroll
      for (int m = 0; m < 3; m++) acc1[m] += wh1*sh1[m];
      #pragma unroll
      for (int m = 0; m < 5; m++) acc2[m] += wh2*sh2[m];
    }
    acc0 = xgrp_sum(acc0);
    #pragma unroll
    for (int m = 0; m < 3; m++) acc1[m] = xgrp_sum(acc1[m]);
    #pragma unroll
    for (int m = 0; m < 5; m++) acc2[m] = xgrp_sum(acc2[m]);
    if (g == 0) {
      a0[n*16 + c] = acc0;
      #pragma unroll
      for (int m = 0; m < 3; m++) a1[n*48 + c*3 + m] = acc1[m];
      #pragma unroll
      for (int m = 0; m < 5; m++) a2[n*80 + c*5 + m] = acc2[m];
    }
  }
}

// ---------------------------------------------------------------------------
// Forward block 1 (last) — persistent wave per node, 8 groups x channel-PAIR.
// ---------------------------------------------------------------------------
__global__ void __launch_bounds__(256, 2)
k_fwd_b1(const float* __restrict__ Wr, const float* __restrict__ br,
         const float* __restrict__ h0_in, const float* __restrict__ h1_in,
         const float* __restrict__ h2_in,
         const float4* __restrict__ uR, const float2* __restrict__ scR,
         const int* __restrict__ colR,
         const int* __restrict__ start_row, const int* __restrict__ deg_row,
         float* __restrict__ a0, int N)
{
  int wid = (blockIdx.x * blockDim.x + threadIdx.x) >> 6;
  int nw  = (gridDim.x * blockDim.x) >> 6;
  int lane = threadIdx.x & 63;
  int g = lane >> 3, cl = lane & 7;
  const float2* Wr2 = (const float2*)Wr;
  const float2* br2 = (const float2*)br;
  const float2* h0_2 = (const float2*)h0_in;
  const float2* h1_2 = (const float2*)h1_in;
  const float2* h2_2 = (const float2*)h2_in;

  float2 wr0[8], wr3[8], wr4[8];
  #pragma unroll
  for (int k = 0; k < 8; k++) {
    wr0[k] = Wr2[k*40 + cl];
    wr3[k] = Wr2[k*40 + 24 + cl];
    wr4[k] = Wr2[k*40 + 32 + cl];
  }
  float2 b0v = br2[cl], b3v = br2[24 + cl], b4v = br2[32 + cl];

  for (int n = wid; n < N; n += nw) {
    float acc0x = 0.f, acc0y = 0.f;
    int i0 = start_row[n] + g, i1 = start_row[n] + deg_row[n];
    float4 Un = {0,0,0,0}; float2 SCn = {0,0};
    float2 h0n = {0.f,0.f}; int coln = 0;
    if (i0 < i1) {
      coln = colR[i0];
      Un = uR[i0]; SCn = scR[i0];
      h0n = h0_2[coln*8 + cl];
    }
    for (int i = i0; i < i1; i += 8) {
      float4 U = Un; float2 SC = SCn; float2 h0c = h0n; int col = coln;
      if (i+8 < i1) {
        coln = colR[i+8];
        Un = uR[i+8]; SCn = scR[i+8];
        h0n = h0_2[coln*8 + cl];
      }
      // issue h1/h2 pair loads early; k-loop below hides their latency
      float2 A0 = h1_2[col*24 + 3*cl + 0];
      float2 A1 = h1_2[col*24 + 3*cl + 1];
      float2 A2 = h1_2[col*24 + 3*cl + 2];
      float2 B0 = h2_2[col*40 + 5*cl + 0];
      float2 B1 = h2_2[col*40 + 5*cl + 1];
      float2 B2 = h2_2[col*40 + 5*cl + 2];
      float2 B3 = h2_2[col*40 + 5*cl + 3];
      float2 B4 = h2_2[col*40 + 5*cl + 4];

      float inv_r = U.w;
      float Ki = KRADf * inv_r;
      float tc = 2.f * SC.y;
      float sprev = 0.f, s = SC.x;
      float w0x = b0v.x, w0y = b0v.y, w3x = b3v.x, w3y = b3v.y, w4x = b4v.x, w4y = b4v.y;
      #pragma unroll
      for (int k = 0; k < 8; k++) {
        float rad = Ki * s;
        w0x += rad*wr0[k].x; w0y += rad*wr0[k].y;
        w3x += rad*wr3[k].x; w3y += rad*wr3[k].y;
        w4x += rad*wr4[k].x; w4y += rad*wr4[k].y;
        float sn = tc*s - sprev; sprev = s; s = sn;
      }
      float sh1[3], sh2[5];
      sh_from_u(U.x, U.y, U.z, sh1, sh2);
      // channel c0 = 2cl holds {A0.x,A0.y,A1.x}; c1 = 2cl+1 holds {A1.y,A2.x,A2.y}
      float S1x = A0.x*sh1[0] + A0.y*sh1[1] + A1.x*sh1[2];
      float S1y = A1.y*sh1[0] + A2.x*sh1[1] + A2.y*sh1[2];
      float S2x = B0.x*sh2[0] + B0.y*sh2[1] + B1.x*sh2[2] + B1.y*sh2[3] + B2.x*sh2[4];
      float S2y = B2.y*sh2[0] + B3.x*sh2[1] + B3.y*sh2[2] + B4.x*sh2[3] + B4.y*sh2[4];
      acc0x += w0x*h0c.x + w3x*S1x + w4x*S2x;
      acc0y += w0y*h0c.y + w3y*S1y + w4y*S2y;
    }
    acc0x = xgrp8_sum(acc0x);
    acc0y = xgrp8_sum(acc0y);
    if (g == 0) ((float2*)a0)[n*8 + cl] = make_float2(acc0x, acc0y);
  }
}

// ---------------------------------------------------------------------------
// Node update (block 0 only): h_out = h_in + a @ U
// ---------------------------------------------------------------------------
__global__ void k_node_update(const float* __restrict__ h0_in,
                              const float* __restrict__ a0, const float* __restrict__ a1,
                              const float* __restrict__ a2,
                              const float* __restrict__ U,
                              float* __restrict__ h0_out, float* __restrict__ h1_out,
                              float* __restrict__ h2_out, int N)
{
  int idx = blockIdx.x * blockDim.x + threadIdx.x;
  int n = idx >> 4, d = idx & 15;
  if (n >= N) return;
  const float* U0 = U;
  const float* U1 = U + 256;
  const float* U2 = U + 512;
  float s = h0_in[n*16 + d];
  #pragma unroll
  for (int c = 0; c < 16; c++) s += a0[n*16 + c] * U0[c*16 + d];
  h0_out[n*16 + d] = s;
  float v1[3] = {0.f, 0.f, 0.f};
  #pragma unroll
  for (int c = 0; c < 16; c++) {
    float u = U1[c*16 + d];
    #pragma unroll
    for (int m = 0; m < 3; m++) v1[m] += a1[n*48 + c*3 + m] * u;
  }
  #pragma unroll
  for (int m = 0; m < 3; m++) h1_out[n*48 + d*3 + m] = v1[m];
  float v2[5] = {0.f, 0.f, 0.f, 0.f, 0.f};
  #pragma unroll
  for (int c = 0; c < 16; c++) {
    float u = U2[c*16 + d];
    #pragma unroll
    for (int m = 0; m < 5; m++) v2[m] += a2[n*80 + c*5 + m] * u;
  }
  #pragma unroll
  for (int m = 0; m < 5; m++) h2_out[n*80 + d*5 + m] = v2[m];
}

// ---------------------------------------------------------------------------
// Readout fwd + bwd fused (unchanged).
// ---------------------------------------------------------------------------
__global__ void __launch_bounds__(256, 1)
k_readout_bwd(const float* __restrict__ h0s1, const float* __restrict__ a0in,
              const float* __restrict__ W_read,
              const float* __restrict__ W1, const float* __restrict__ b1,
              const float* __restrict__ W2, const float* __restrict__ b2,
              const float* __restrict__ U0b1,
              float* __restrict__ g0, float* __restrict__ ga0,
              float* __restrict__ partials, int N)
{
  __shared__ float sWr[256], sW1[256], sU[256], sb1[16], sW2[16], sb2;
  __shared__ float swave[4];
  {
    int t = threadIdx.x;
    if (t < 256) { sWr[t] = W_read[t]; sW1[t] = W1[t]; sU[t] = U0b1[t]; }
    if (t < 16)  { sb1[t] = b1[t]; sW2[t] = W2[t]; }
    if (t == 0)  sb2 = b2[0];
  }
  __syncthreads();
  int n = blockIdx.x * blockDim.x + threadIdx.x;
  float site = 0.f;
  if (n < N) {
    float h[16], av[16], inv[16], dt[16], g0v[16];
    #pragma unroll
    for (int d = 0; d < 16; d++) av[d] = a0in[n*16 + d];
    #pragma unroll
    for (int d = 0; d < 16; d++) {
      float s = h0s1[n*16 + d];
      #pragma unroll
      for (int cc = 0; cc < 16; cc++) s += av[cc] * sU[cc*16 + d];
      h[d] = s;
    }
    #pragma unroll
    for (int j = 0; j < 16; j++) {
      float s = 0.f;
      #pragma unroll
      for (int d = 0; d < 16; d++) s += h[d] * sWr[d*16 + j];
      inv[j] = s;
    }
    site = sb2;
    #pragma unroll
    for (int c = 0; c < 16; c++) {
      float t = sb1[c];
      #pragma unroll
      for (int j = 0; j < 16; j++) t += inv[j] * sW1[j*16 + c];
      float sg = 1.f / (1.f + expf(-t));
      float w2v = sW2[c];
      site += t * sg * w2v;
      dt[c] = w2v * sg * (1.f + t * (1.f - sg));
    }
    float dinv[16];
    #pragma unroll
    for (int j = 0; j < 16; j++) {
      float s = 0.f;
      #pragma unroll
      for (int c = 0; c < 16; c++) s += dt[c] * sW1[j*16 + c];
      dinv[j] = s;
    }
    #pragma unroll
    for (int d = 0; d < 16; d++) {
      float s = 0.f;
      #pragma unroll
      for (int j = 0; j < 16; j++) s += dinv[j] * sWr[d*16 + j];
      g0v[d] = s;
      g0[n*16 + d] = s;
    }
    #pragma unroll
    for (int c = 0; c < 16; c++) {
      float s = 0.f;
      #pragma unroll
      for (int d = 0; d < 16; d++) s += g0v[d] * sU[c*16 + d];
      ga0[n*16 + c] = s;
    }
  }
  #pragma unroll
  for (int off = 32; off; off >>= 1) site += __shfl_down(site, off, 64);
  int wave = threadIdx.x >> 6;
  if ((threadIdx.x & 63) == 0) swave[wave] = site;
  __syncthreads();
  if (threadIdx.x == 0)
    partials[blockIdx.x] = swave[0] + swave[1] + swave[2] + swave[3];
}

// Sum per-block partials into energy (single tiny block).
__global__ void k_energy(const float* __restrict__ partials, int nb,
                         float* __restrict__ energy)
{
  int t = threadIdx.x;           // 128 threads (2 waves)
  float s = 0.f;
  for (int i = t; i < nb; i += 128) s += partials[i];
  #pragma unroll
  for (int off = 32; off; off >>= 1) s += __shfl_down(s, off, 64);
  __shared__ float sw[2];
  if ((t & 63) == 0) sw[t >> 6] = s;
  __syncthreads();
  if (t == 0) energy[0] = sw[0] + sw[1];
}

// ---------------------------------------------------------------------------
// ga = g @ U^T (full, for block 0 backward)
// ---------------------------------------------------------------------------
__global__ void k_ga(const float* __restrict__ g0, const float* __restrict__ g1,
                     const float* __restrict__ g2, const float* __restrict__ U,
                     float* __restrict__ ga0, float* __restrict__ ga1, float* __restrict__ ga2,
                     int N)
{
  int idx = blockIdx.x * blockDim.x + threadIdx.x;
  int n = idx >> 4, c = idx & 15;
  if (n >= N) return;
  const float* U0 = U;
  const float* U1 = U + 256;
  const float* U2 = U + 512;
  float s = 0.f;
  #pragma unroll
  for (int d = 0; d < 16; d++) s += g0[n*16 + d] * U0[c*16 + d];
  ga0[n*16 + c] = s;
  float v1[3] = {0.f, 0.f, 0.f};
  #pragma unroll
  for (int d = 0; d < 16; d++) {
    float u = U1[c*16 + d];
    #pragma unroll
    for (int m = 0; m < 3; m++) v1[m] += g1[n*48 + d*3 + m] * u;
  }
  #pragma unroll
  for (int m = 0; m < 3; m++) ga1[n*48 + c*3 + m] = v1[m];
  float v2[5] = {0.f, 0.f, 0.f, 0.f, 0.f};
  #pragma unroll
  for (int d = 0; d < 16; d++) {
    float u = U2[c*16 + d];
    #pragma unroll
    for (int m = 0; m < 5; m++) v2[m] += g2[n*80 + d*5 + m] * u;
  }
  #pragma unroll
  for (int m = 0; m < 5; m++) ga2[n*80 + c*5 + m] = v2[m];
}

// ---------------------------------------------------------------------------
// Backward block 1, col-centric — persistent wave per node, 8 x channel-pair.
// Merged k-loop: w/t/P/Q in one pass; gr = inv_r*(KPI5*P - Q).
// ---------------------------------------------------------------------------
__global__ void __launch_bounds__(256, 2)
k_bwd_b1_col(const float* __restrict__ Wr, const float* __restrict__ br,
             const float* __restrict__ h0_in, const float* __restrict__ h1_in,
             const float* __restrict__ h2_in,
             const float* __restrict__ ga0,
             const float4* __restrict__ uC, const float2* __restrict__ scC,
             const int* __restrict__ rowC,
             const int* __restrict__ start_col, const int* __restrict__ deg_col,
             float* __restrict__ g0, float* __restrict__ g1, float* __restrict__ g2,
             float* __restrict__ dv_col, int N)
{
  int wid = (blockIdx.x * blockDim.x + threadIdx.x) >> 6;
  int nw  = (gridDim.x * blockDim.x) >> 6;
  int lane = threadIdx.x & 63;
  int g = lane >> 3, cl = lane & 7;
  const float2* Wr2 = (const float2*)Wr;
  const float2* br2 = (const float2*)br;
  const float2* h0_2 = (const float2*)h0_in;
  const float2* h1_2 = (const float2*)h1_in;
  const float2* h2_2 = (const float2*)h2_in;
  const float2* ga0_2 = (const float2*)ga0;

  float2 wr0[8], wr3[8], wr4[8];
  #pragma unroll
  for (int k = 0; k < 8; k++) {
    wr0[k] = Wr2[k*40 + cl];
    wr3[k] = Wr2[k*40 + 24 + cl];
    wr4[k] = Wr2[k*40 + 32 + cl];
  }
  float2 b0v = br2[cl], b3v = br2[24 + cl], b4v = br2[32 + cl];

  for (int n = wid; n < N; n += nw) {
    float2 h0c = h0_2[n*8 + cl];
    float2 A0 = h1_2[n*24 + 3*cl + 0];
    float2 A1 = h1_2[n*24 + 3*cl + 1];
    float2 A2 = h1_2[n*24 + 3*cl + 2];
    float h1a[3] = {A0.x, A0.y, A1.x};
    float h1b[3] = {A1.y, A2.x, A2.y};
    float2 B0 = h2_2[n*40 + 5*cl + 0];
    float2 B1 = h2_2[n*40 + 5*cl + 1];
    float2 B2 = h2_2[n*40 + 5*cl + 2];
    float2 B3 = h2_2[n*40 + 5*cl + 3];
    float2 B4 = h2_2[n*40 + 5*cl + 4];
    float h2a[5] = {B0.x, B0.y, B1.x, B1.y, B2.x};
    float h2b[5] = {B2.y, B3.x, B3.y, B4.x, B4.y};

    float accg0x = 0.f, accg0y = 0.f;
    float accg1a[3] = {0.f,0.f,0.f}, accg1b[3] = {0.f,0.f,0.f};
    float accg2a[5] = {0.f,0.f,0.f,0.f,0.f}, accg2b[5] = {0.f,0.f,0.f,0.f,0.f};

    int i0 = start_col[n] + g, i1 = start_col[n] + deg_col[n];
    float4 Un = {0,0,0,0}; float2 SCn = {0,0};
    float2 dm0n = {0.f,0.f};
    if (i0 < i1) {
      Un = uC[i0]; SCn = scC[i0];
      dm0n = ga0_2[rowC[i0]*8 + cl];
    }
    for (int i = i0; i < i1; i += 8) {
      float4 U = Un; float2 SC = SCn; float2 dm0 = dm0n;
      if (i + 8 < i1) {
        Un = uC[i+8]; SCn = scC[i+8];
        dm0n = ga0_2[rowC[i+8]*8 + cl];
      }
      float sh1[3], sh2[5];
      sh_from_u(U.x, U.y, U.z, sh1, sh2);
      float S1x = h1a[0]*sh1[0] + h1a[1]*sh1[1] + h1a[2]*sh1[2];
      float S1y = h1b[0]*sh1[0] + h1b[1]*sh1[1] + h1b[2]*sh1[2];
      float S2x = h2a[0]*sh2[0] + h2a[1]*sh2[1] + h2a[2]*sh2[2] + h2a[3]*sh2[3] + h2a[4]*sh2[4];
      float S2y = h2b[0]*sh2[0] + h2b[1]*sh2[1] + h2b[2]*sh2[2] + h2b[3]*sh2[3] + h2b[4]*sh2[4];
      float dw0x = dm0.x*h0c.x, dw0y = dm0.y*h0c.y;
      float dw3x = dm0.x*S1x,   dw3y = dm0.y*S1y;
      float dw4x = dm0.x*S2x,   dw4y = dm0.y*S2y;

      float inv_r = U.w;
      float Ki = KRADf * inv_r;
      float tc = 2.f * SC.y;
      float sprev = 0.f, s = SC.x, cprev = 1.f, cc = SC.y;
      float w0x = b0v.x, w0y = b0v.y, w3x = b3v.x, w3y = b3v.y, w4x = b4v.x, w4y = b4v.y;
      float P = 0.f, Q = 0.f;
      #pragma unroll
      for (int k = 0; k < 8; k++) {
        float rad = Ki * s;
        w0x += rad*wr0[k].x; w0y += rad*wr0[k].y;
        w3x += rad*wr3[k].x; w3y += rad*wr3[k].y;
        w4x += rad*wr4[k].x; w4y += rad*wr4[k].y;
        float t = dw0x*wr0[k].x + dw0y*wr0[k].y
                + dw3x*wr3[k].x + dw3y*wr3[k].y
                + dw4x*wr4[k].x + dw4y*wr4[k].y;
        P += (t*cc) * (float)(k+1);
        Q += t*rad;
        float sn = tc*s - sprev; sprev = s; s = sn;
        float cn = tc*cc - cprev; cprev = cc; cc = cn;
      }
      accg0x += dm0.x*w0x; accg0y += dm0.y*w0y;
      float t3x = dm0.x*w3x, t3y = dm0.y*w3y;
      float t4x = dm0.x*w4x, t4y = dm0.y*w4y;
      #pragma unroll
      for (int m = 0; m < 3; m++) { accg1a[m] += t3x*sh1[m]; accg1b[m] += t3y*sh1[m]; }
      #pragma unroll
      for (int m = 0; m < 5; m++) { accg2a[m] += t4x*sh2[m]; accg2b[m] += t4y*sh2[m]; }

      float q1x = t3x*h1a[0] + t3y*h1b[0];
      float q1y = t3x*h1a[1] + t3y*h1b[1];
      float q1z = t3x*h1a[2] + t3y*h1b[2];
      float q0 = t4x*h2a[0] + t4y*h2b[0];
      float q1 = t4x*h2a[1] + t4y*h2b[1];
      float q2 = t4x*h2a[2] + t4y*h2b[2];
      float q3 = t4x*h2a[3] + t4y*h2b[3];
      float q4 = t4x*h2a[4] + t4y*h2b[4];

      float gr = (KPI5f*P - Q) * inv_r;
      float gux = SQRT3f*q1x + SQRT15f*(U.y*q0 + U.z*q3 + U.x*q4);
      float guy = SQRT3f*q1y + SQRT15f*(U.x*q0 + U.z*q1 - U.y*q4);
      float guz = SQRT3f*q1z + SQRT15f*U.y*q1 + 3.f*SQRT5f*U.z*q2 + SQRT15f*U.x*q3;

      gr  = grp8_sum(gr);
      gux = grp8_sum(gux);
      guy = grp8_sum(guy);
      guz = grp8_sum(guz);

      if (cl == 0) {
        float gdotu = gux*U.x + guy*U.y + guz*U.z;
        dv_col[i*3+0] = gr*U.x + (gux - gdotu*U.x)*inv_r;
        dv_col[i*3+1] = gr*U.y + (guy - gdotu*U.y)*inv_r;
        dv_col[i*3+2] = gr*U.z + (guz - gdotu*U.z)*inv_r;
      }
    }
    accg0x = xgrp8_sum(accg0x); accg0y = xgrp8_sum(accg0y);
    #pragma unroll
    for (int m = 0; m < 3; m++) { accg1a[m] = xgrp8_sum(accg1a[m]); accg1b[m] = xgrp8_sum(accg1b[m]); }
    #pragma unroll
    for (int m = 0; m < 5; m++) { accg2a[m] = xgrp8_sum(accg2a[m]); accg2b[m] = xgrp8_sum(accg2b[m]); }
    if (g == 0) {
      float2* g0_2 = (float2*)g0;
      float2 old = g0_2[n*8 + cl];
      g0_2[n*8 + cl] = make_float2(old.x + accg0x, old.y + accg0y);
      float2* g1_2 = (float2*)g1;
      g1_2[n*24 + 3*cl + 0] = make_float2(accg1a[0], accg1a[1]);
      g1_2[n*24 + 3*cl + 1] = make_float2(accg1a[2], accg1b[0]);
      g1_2[n*24 + 3*cl + 2] = make_float2(accg1b[1], accg1b[2]);
      float2* g2_2 = (float2*)g2;
      g2_2[n*40 + 5*cl + 0] = make_float2(accg2a[0], accg2a[1]);
      g2_2[n*40 + 5*cl + 1] = make_float2(accg2a[2], accg2a[3]);
      g2_2[n*40 + 5*cl + 2] = make_float2(accg2a[4], accg2b[0]);
      g2_2[n*40 + 5*cl + 3] = make_float2(accg2b[1], accg2b[2]);
      g2_2[n*40 + 5*cl + 4] = make_float2(accg2b[3], accg2b[4]);
    }
  }
}

// ---------------------------------------------------------------------------
// Backward block 0, row-centric — persistent wave per node, 8 x channel-pair.
// ---------------------------------------------------------------------------
__global__ void __launch_bounds__(256, 2)
k_bwd_b0_row(const float* __restrict__ Wr, const float* __restrict__ br,
             const float* __restrict__ h0_in,
             const float* __restrict__ ga0, const float* __restrict__ ga1,
             const float* __restrict__ ga2,
             const float4* __restrict__ uR, const float2* __restrict__ scR,
             const int* __restrict__ colR,
             const int* __restrict__ start_row, const int* __restrict__ deg_row,
             float* __restrict__ dv_row, int N)
{
  int wid = (blockIdx.x * blockDim.x + threadIdx.x) >> 6;
  int nw  = (gridDim.x * blockDim.x) >> 6;
  int lane = threadIdx.x & 63;
  int g = lane >> 3, cl = lane & 7;
  const float2* Wr2 = (const float2*)Wr;
  const float2* br2 = (const float2*)br;
  const float2* h0_2 = (const float2*)h0_in;
  const float2* ga0_2 = (const float2*)ga0;
  const float2* ga1_2 = (const float2*)ga1;
  const float2* ga2_2 = (const float2*)ga2;

  float2 wr0[8], wr1[8], wr2[8];
  #pragma unroll
  for (int k = 0; k < 8; k++) {
    wr0[k] = Wr2[k*40 + cl];
    wr1[k] = Wr2[k*40 + 8 + cl];
    wr2[k] = Wr2[k*40 + 16 + cl];
  }
  float2 b1v = br2[8 + cl], b2v = br2[16 + cl];

  for (int n = wid; n < N; n += nw) {
    float2 dm0 = ga0_2[n*8 + cl];
    float2 A0 = ga1_2[n*24 + 3*cl + 0];
    float2 A1 = ga1_2[n*24 + 3*cl + 1];
    float2 A2 = ga1_2[n*24 + 3*cl + 2];
    float dm1a[3] = {A0.x, A0.y, A1.x};
    float dm1b[3] = {A1.y, A2.x, A2.y};
    float2 B0 = ga2_2[n*40 + 5*cl + 0];
    float2 B1 = ga2_2[n*40 + 5*cl + 1];
    float2 B2 = ga2_2[n*40 + 5*cl + 2];
    float2 B3 = ga2_2[n*40 + 5*cl + 3];
    float2 B4 = ga2_2[n*40 + 5*cl + 4];
    float dm2a[5] = {B0.x, B0.y, B1.x, B1.y, B2.x};
    float dm2b[5] = {B2.y, B3.x, B3.y, B4.x, B4.y};

    int i0 = start_row[n] + g, i1 = start_row[n] + deg_row[n];
    float4 Un = {0,0,0,0}; float2 SCn = {0,0};
    float2 h0n = {0.f,0.f};
    if (i0 < i1) {
      Un = uR[i0]; SCn = scR[i0];
      h0n = h0_2[colR[i0]*8 + cl];
    }
    for (int i = i0; i < i1; i += 8) {
      float4 U = Un; float2 SC = SCn; float2 h0c = h0n;
      if (i + 8 < i1) {
        Un = uR[i+8]; SCn = scR[i+8];
        h0n = h0_2[colR[i+8]*8 + cl];
      }
      float sh1[3], sh2[5];
      sh_from_u(U.x, U.y, U.z, sh1, sh2);
      float T1x = dm1a[0]*sh1[0] + dm1a[1]*sh1[1] + dm1a[2]*sh1[2];
      float T1y = dm1b[0]*sh1[0] + dm1b[1]*sh1[1] + dm1b[2]*sh1[2];
      float T2x = dm2a[0]*sh2[0] + dm2a[1]*sh2[1] + dm2a[2]*sh2[2] + dm2a[3]*sh2[3] + dm2a[4]*sh2[4];
      float T2y = dm2b[0]*sh2[0] + dm2b[1]*sh2[1] + dm2b[2]*sh2[2] + dm2b[3]*sh2[3] + dm2b[4]*sh2[4];
      float dw0x = dm0.x*h0c.x, dw0y = dm0.y*h0c.y;
      float dw1x = h0c.x*T1x,  dw1y = h0c.y*T1y;
      float dw2x = h0c.x*T2x,  dw2y = h0c.y*T2y;

      float inv_r = U.w;
      float Ki = KRADf * inv_r;
      float tc = 2.f * SC.y;
      float sprev = 0.f, s = SC.x, cprev = 1.f, cc = SC.y;
      float w1x = b1v.x, w1y = b1v.y, w2x = b2v.x, w2y = b2v.y;
      float P = 0.f, Q = 0.f;
      #pragma unroll
      for (int k = 0; k < 8; k++) {
        float rad = Ki * s;
        w1x += rad*wr1[k].x; w1y += rad*wr1[k].y;
        w2x += rad*wr2[k].x; w2y += rad*wr2[k].y;
        float t = dw0x*wr0[k].x + dw0y*wr0[k].y
                + dw1x*wr1[k].x + dw1y*wr1[k].y
                + dw2x*wr2[k].x + dw2y*wr2[k].y;
        P += (t*cc) * (float)(k+1);
        Q += t*rad;
        float sn = tc*s - sprev; sprev = s; s = sn;
        float cn = tc*cc - cprev; cprev = cc; cc = cn;
      }
      float w1hx = w1x*h0c.x, w1hy = w1y*h0c.y;
      float w2hx = w2x*h0c.x, w2hy = w2y*h0c.y;
      float q1x = dm1a[0]*w1hx + dm1b[0]*w1hy;
      float q1y = dm1a[1]*w1hx + dm1b[1]*w1hy;
      float q1z = dm1a[2]*w1hx + dm1b[2]*w1hy;
      float q0 = dm2a[0]*w2hx + dm2b[0]*w2hy;
      float q1 = dm2a[1]*w2hx + dm2b[1]*w2hy;
      float q2 = dm2a[2]*w2hx + dm2b[2]*w2hy;
      float q3 = dm2a[3]*w2hx + dm2b[3]*w2hy;
      float q4 = dm2a[4]*w2hx + dm2b[4]*w2hy;

      float gr = (KPI5f*P - Q) * inv_r;
      float gux = SQRT3f*q1x + SQRT15f*(U.y*q0 + U.z*q3 + U.x*q4);
      float guy = SQRT3f*q1y + SQRT15f*(U.x*q0 + U.z*q1 - U.y*q4);
      float guz = SQRT3f*q1z + SQRT15f*U.y*q1 + 3.f*SQRT5f*U.z*q2 + SQRT15f*U.x*q3;

      gr  = grp8_sum(gr);
      gux = grp8_sum(gux);
      guy = grp8_sum(guy);
      guz = grp8_sum(guz);

      if (cl == 0) {
        float gdotu = gux*U.x + guy*U.y + guz*U.z;
        dv_row[i*3+0] = gr*U.x + (gux - gdotu*U.x)*inv_r;
        dv_row[i*3+1] = gr*U.y + (guy - gdotu*U.y)*inv_r;
        dv_row[i*3+2] = gr*U.z + (guz - gdotu*U.z)*inv_r;
      }
    }
  }
}

// ---------------------------------------------------------------------------
// Force assembly: 16 lanes per node.
// ---------------------------------------------------------------------------
__global__ void k_force(const int* __restrict__ start_row, const int* __restrict__ deg_row,
                        const int* __restrict__ cposR,
                        const int* __restrict__ start_col, const int* __restrict__ deg_col,
                        const int* __restrict__ rposC,
                        const float* __restrict__ dv_col, const float* __restrict__ dv_row,
                        float* __restrict__ force, int N)
{
  int idx = blockIdx.x * blockDim.x + threadIdx.x;
  int n = idx >> 4, l = idx & 15;
  if (n >= N) return;
  float fx = 0.f, fy = 0.f, fz = 0.f;
  int c0 = start_col[n], c1 = c0 + deg_col[n];
  for (int i = c0 + l; i < c1; i += 16) {
    int rp = rposC[i];
    fx += dv_col[i*3+0] + dv_row[rp*3+0];
    fy += dv_col[i*3+1] + dv_row[rp*3+1];
    fz += dv_col[i*3+2] + dv_row[rp*3+2];
  }
  int r0 = start_row[n], r1 = r0 + deg_row[n];
  for (int i = r0 + l; i < r1; i += 16) {
    int cp = cposR[i];
    fx -= dv_row[i*3+0] + dv_col[cp*3+0];
    fy -= dv_row[i*3+1] + dv_col[cp*3+1];
    fz -= dv_row[i*3+2] + dv_col[cp*3+2];
  }
  fx = grp16_sum(fx); fy = grp16_sum(fy); fz = grp16_sum(fz);
  if (l == 0) {
    force[n*3+0] = fx; force[n*3+1] = fy; force[n*3+2] = fz;
  }
}

// ---------------------------------------------------------------------------
extern "C" void kernel_launch(void* const* d_in, const int* in_sizes, int n_in,
                              void* d_out, int out_size, void* d_ws, size_t ws_size,
                              hipStream_t stream)
{
  const float* pos    = (const float*)d_in[0];
  const int*   z      = (const int*)  d_in[1];
  const int*   ei     = (const int*)  d_in[2];
  const float* emb    = (const float*)d_in[3];
  const float* W_init = (const float*)d_in[4];
  const float* Wr     = (const float*)d_in[5];   // (2, 8, 80)
  const float* br     = (const float*)d_in[6];   // (2, 80)
  const float* W_out  = (const float*)d_in[7];   // (2, 3, 16, 16)
  const float* W_read = (const float*)d_in[8];
  const float* W1     = (const float*)d_in[9];
  const float* b1     = (const float*)d_in[10];
  const float* W2     = (const float*)d_in[11];
  const float* b2     = (const float*)d_in[12];

  const int N = in_sizes[0] / 3;
  const int E = in_sizes[2] / 2;

  const int BLK = 256;
  const int NB_READOUT = cdiv(N, BLK);
  // Persistent grid for wave-per-node kernels.
  const int PBLK = (N < 8192) ? cdiv(N, 4) : 2048;

  float* f = (float*)d_ws;
  float4* uR  = (float4*)f; f += (size_t)E*4;
  float4* uC  = (float4*)f; f += (size_t)E*4;
  float2* scR = (float2*)f; f += (size_t)E*2;
  float2* scC = (float2*)f; f += (size_t)E*2;
  float* h0_s0 = f; f += (size_t)N*16;
  float* h0_s1 = f; f += (size_t)N*16;
  float* h1_s1 = f; f += (size_t)N*48;
  float* h2_s1 = f; f += (size_t)N*80;
  float* a0    = f; f += (size_t)N*16;   // block-0 agg, then block-1 agg, then ga0_b0
  float* a1    = f; f += (size_t)N*48;   //                                 ga1_b0
  float* a2    = f; f += (size_t)N*80;   //                                 ga2_b0
  float* ga0b1 = f; f += (size_t)N*16;   // readout's ga0 (dE/da0 block 1)
  float* g0    = f; f += (size_t)N*16;
  float* g1    = f; f += (size_t)N*48;
  float* g2    = f; f += (size_t)N*80;
  float* dv_c  = f; f += (size_t)E*3;    // dv from bwd b1, col order
  float* dv_r  = f; f += (size_t)E*3;    // dv from bwd b0, row order
  float* partials = f; f += (size_t)NB_READOUT;
  int* ip = (int*)f;
  int* cursors   = ip; ip += 2;          // cursors+deg contiguous -> one memset
  int* deg_row   = ip; ip += N;
  int* deg_col   = ip; ip += N;
  int* start_row = ip; ip += N;
  int* start_col = ip; ip += N;
  int* cur_row   = ip; ip += N;
  int* cur_col   = ip; ip += N;
  int* colR      = ip; ip += E;
  int* cposR     = ip; ip += E;
  int* rowC      = ip; ip += E;
  int* rposC     = ip; ip += E;

  float* out    = (float*)d_out;
  float* energy = out;
  float* force  = out + 1;

  (void)hipMemsetAsync(cursors, 0, (size_t)(2 + 2*N) * sizeof(int), stream);

  // ---- CSR build (scan-free) + compact geometry in both orders ----
  k_hist<<<cdiv(E, BLK), BLK, 0, stream>>>(ei, E, deg_row, deg_col);
  k_alloc<<<cdiv(N, BLK), BLK, 0, stream>>>(deg_row, deg_col, start_row, cur_row,
                                            start_col, cur_col, cursors, N);
  k_scatter_geom<<<cdiv(E, BLK), BLK, 0, stream>>>(pos, ei, E, cur_row, cur_col,
                                                   uR, scR, uC, scC,
                                                   colR, cposR, rowC, rposC);

  k_node_init<<<cdiv(N, BLK), BLK, 0, stream>>>(emb, z, W_init, h0_s0, N);

  // ---- forward block 0 ----
  k_fwd_b0<<<PBLK, BLK, 0, stream>>>(Wr, br, h0_s0, uR, scR, colR,
                                     start_row, deg_row, a0, a1, a2, N);
  k_node_update<<<cdiv(N*16, BLK), BLK, 0, stream>>>(h0_s0, a0, a1, a2,
                                                     W_out, h0_s1, h1_s1, h2_s1, N);

  // ---- forward block 1 (h0_s2 folded into readout) ----
  k_fwd_b1<<<PBLK, BLK, 0, stream>>>(Wr + 640, br + 80,
                                     h0_s1, h1_s1, h2_s1, uR, scR, colR,
                                     start_row, deg_row, a0, N);

  // ---- readout fwd + bwd (includes block-1 h0 update; emits g0, ga0b1) ----
  k_readout_bwd<<<NB_READOUT, BLK, 0, stream>>>(h0_s1, a0, W_read, W1, b1, W2, b2,
                                                W_out + 768, g0, ga0b1, partials, N);
  k_energy<<<1, 128, 0, stream>>>(partials, NB_READOUT, energy);

  // ---- backward block 1 ----
  k_bwd_b1_col<<<PBLK, BLK, 0, stream>>>(Wr + 640, br + 80,
                                         h0_s1, h1_s1, h2_s1, ga0b1,
                                         uC, scC, rowC, start_col, deg_col,
                                         g0, g1, g2, dv_c, N);

  // ---- backward block 0 ----
  k_ga<<<cdiv(N*16, BLK), BLK, 0, stream>>>(g0, g1, g2, W_out, a0, a1, a2, N);
  k_bwd_b0_row<<<PBLK, BLK, 0, stream>>>(Wr, br, h0_s0,
                                         a0, a1, a2, uR, scR, colR,
                                         start_row, deg_row, dv_r, N);

  // ---- force assembly ----
  k_force<<<cdiv(N*16, BLK), BLK, 0, stream>>>(start_row, deg_row, cposR,
                                               start_col, deg_col, rposC,
                                               dv_c, dv_r, force, N);
}

// Round 3
// 473.434 us; speedup vs baseline: 1.8992x; 1.0417x over previous
//
#include <hip/hip_runtime.h>
#include <math.h>

#ifndef M_PI
#define M_PI 3.14159265358979323846
#endif

static inline int cdiv(int a, int b){ return (a + b - 1) / b; }

#define SQRT3f  1.7320508075688772f
#define SQRT5f  2.23606797749979f
#define SQRT15f 3.872983346207417f
#define KRADf   0.6324555320336759f      /* sqrt(2/R_MAX), R_MAX=5 */
#define PI5f    0.6283185307179586f      /* pi/5 */
#define KPI5f   (KRADf * PI5f)

// ---------------------------------------------------------------------------
// R2 post-mortem: 2-ch layout needed 104 VGPR -> crossed the 64-reg tier
// (8 -> 4 waves/SIMD), kernel went latency-bound (VALUBusy 68->45%), net
// REGRESSION despite fewer instructions. Lesson: for these gather-heavy
// loops, stay under 64 VGPR. This round: 16-lane layout (r0, 60 VGPR)
// + merged P/Q k-loop (kills draddr[8] array + separate gr-dot pass)
// + fused rad/w recurrence (kills rad[8] array). No launch_bounds on the
// edge kernels (default allocator lands them in the 64-tier w/o spill).
// ---------------------------------------------------------------------------

__device__ __forceinline__ float grp16_sum(float v){
  v += __shfl_xor(v, 1, 64);
  v += __shfl_xor(v, 2, 64);
  v += __shfl_xor(v, 4, 64);
  v += __shfl_xor(v, 8, 64);
  return v;
}
__device__ __forceinline__ float xgrp_sum(float v){    // across 4 edge-groups
  v += __shfl_xor(v, 16, 64);
  v += __shfl_xor(v, 32, 64);
  return v;
}

// sh from unit vector (8 ops)
__device__ __forceinline__ void sh_from_u(float ux, float uy, float uz,
                                          float* sh1, float* sh2)
{
  sh1[0] = SQRT3f*ux; sh1[1] = SQRT3f*uy; sh1[2] = SQRT3f*uz;
  sh2[0] = SQRT15f*ux*uy;
  sh2[1] = SQRT15f*uy*uz;
  sh2[2] = 0.5f*SQRT5f*(3.f*uz*uz - 1.f);
  sh2[3] = SQRT15f*ux*uz;
  sh2[4] = 0.5f*SQRT15f*(ux*ux - uy*uy);
}

// NOTE (r16 post-mortem, carried forward): precomputing rad/draddr into a
// streamed per-edge buffer regressed (prefetch state spilled to scratch,
// +100 MB HBM). Recompute-in-register stays. Bwd kernels use a MERGED
// k-loop (harness-verified in R2): w and t accumulated in one pass,
// draddr never materialized: gr = inv_r*(KPI5*P - Q),
// P = sum t_k*(k+1)*cos_k, Q = sum t_k*rad_k.

// ---------------------------------------------------------------------------
// Degree histogram (E-parallel)
// ---------------------------------------------------------------------------
__global__ void k_hist(const int* __restrict__ ei, int E,
                       int* __restrict__ deg_row, int* __restrict__ deg_col)
{
  int e = blockIdx.x * blockDim.x + threadIdx.x;
  if (e >= E) return;
  atomicAdd(&deg_row[ei[e]], 1);
  atomicAdd(&deg_col[ei[E + e]], 1);
}

// ---------------------------------------------------------------------------
// Scan-free segment allocation: wave-aggregated atomicAdd on global cursors.
// ---------------------------------------------------------------------------
__global__ void k_alloc(const int* __restrict__ deg_row, const int* __restrict__ deg_col,
                        int* __restrict__ start_row, int* __restrict__ cur_row,
                        int* __restrict__ start_col, int* __restrict__ cur_col,
                        int* __restrict__ cursors, int N)
{
  int idx = blockIdx.x * blockDim.x + threadIdx.x;
  int lane = threadIdx.x & 63;
  #pragma unroll
  for (int which = 0; which < 2; which++) {
    const int* deg = which ? deg_col : deg_row;
    int* start = which ? start_col : start_row;
    int* cur   = which ? cur_col   : cur_row;
    int v = (idx < N) ? deg[idx] : 0;
    int incl = v;
    #pragma unroll
    for (int d = 1; d < 64; d <<= 1) {
      int y = __shfl_up(incl, d, 64);
      if (lane >= d) incl += y;
    }
    int wtot = __shfl(incl, 63, 64);
    int base = 0;
    if (lane == 63) base = atomicAdd(&cursors[which], wtot);
    base = __shfl(base, 63, 64);
    if (idx < N) { int st = base + incl - v; start[idx] = st; cur[idx] = st; }
  }
}

// ---------------------------------------------------------------------------
// Scatter + compact geometry in BOTH CSR orders.
// ---------------------------------------------------------------------------
__global__ void k_scatter_geom(const float* __restrict__ pos, const int* __restrict__ ei, int E,
                               int* __restrict__ cur_row, int* __restrict__ cur_col,
                               float4* __restrict__ uR, float2* __restrict__ scR,
                               float4* __restrict__ uC, float2* __restrict__ scC,
                               int* __restrict__ colR, int* __restrict__ cposR,
                               int* __restrict__ rowC, int* __restrict__ rposC)
{
  int e = blockIdx.x * blockDim.x + threadIdx.x;
  if (e >= E) return;
  int row = ei[e], col = ei[E + e];
  int pr = atomicAdd(&cur_row[row], 1);
  int pc = atomicAdd(&cur_col[col], 1);
  colR[pr] = col; cposR[pr] = pc;
  rowC[pc] = row; rposC[pc] = pr;

  float px = pos[row*3+0] - pos[col*3+0];
  float py = pos[row*3+1] - pos[col*3+1];
  float pz = pos[row*3+2] - pos[col*3+2];
  float r2 = px*px + py*py + pz*pz + 1e-12f;
  float r = sqrtf(r2);
  float inv_r = 1.0f / r;
  float ux = px*inv_r, uy = py*inv_r, uz = pz*inv_r;
  float s1, c1;
  sincosf(r * PI5f, &s1, &c1);
  float4 u4 = make_float4(ux, uy, uz, inv_r);
  float2 sc = make_float2(s1, c1);
  uR[pr] = u4; scR[pr] = sc;
  uC[pc] = u4; scC[pc] = sc;
}

// ---------------------------------------------------------------------------
// h0_init[n,:] = emb[z[n],:] @ W_init
// ---------------------------------------------------------------------------
__global__ void k_node_init(const float* __restrict__ emb, const int* __restrict__ z,
                            const float* __restrict__ W_init, float* __restrict__ h0, int N)
{
  __shared__ float sW[256];
  if (threadIdx.x < 256) sW[threadIdx.x] = W_init[threadIdx.x];
  __syncthreads();
  int n = blockIdx.x * blockDim.x + threadIdx.x;
  if (n >= N) return;
  const float* e = emb + z[n]*16;
  float ev[16];
  #pragma unroll
  for (int k = 0; k < 16; k++) ev[k] = e[k];
  #pragma unroll
  for (int c = 0; c < 16; c++) {
    float s = 0.f;
    #pragma unroll
    for (int k = 0; k < 16; k++) s += ev[k] * sW[k*16+c];
    h0[n*16+c] = s;
  }
}

// ---------------------------------------------------------------------------
// Forward block 0 — persistent wave per node (4 groups x 16 channels).
// Fused rad/w recurrence (no rad[] array).
// ---------------------------------------------------------------------------
__global__ void k_fwd_b0(const float* __restrict__ Wr, const float* __restrict__ br,
                         const float* __restrict__ h0_in,
                         const float4* __restrict__ uR, const float2* __restrict__ scR,
                         const int* __restrict__ colR,
                         const int* __restrict__ start_row, const int* __restrict__ deg_row,
                         float* __restrict__ a0, float* __restrict__ a1, float* __restrict__ a2,
                         int N)
{
  int wid = (blockIdx.x * blockDim.x + threadIdx.x) >> 6;
  int nw  = (gridDim.x * blockDim.x) >> 6;
  int lane = threadIdx.x & 63;
  int g = lane >> 4, c = lane & 15;
  float wr0[8], wr1[8], wr2[8];
  #pragma unroll
  for (int k = 0; k < 8; k++) {
    wr0[k] = Wr[k*80 + c];
    wr1[k] = Wr[k*80 + 16 + c];
    wr2[k] = Wr[k*80 + 32 + c];
  }
  float b0v = br[c], b1v = br[16 + c], b2v = br[32 + c];

  for (int n = wid; n < N; n += nw) {
    float acc0 = 0.f, acc1[3] = {0.f,0.f,0.f}, acc2[5] = {0.f,0.f,0.f,0.f,0.f};

    int i0 = start_row[n] + g, i1 = start_row[n] + deg_row[n];
    float4 Un = {0,0,0,0}; float2 SCn = {0,0};
    float h0n = 0.f;
    if (i0 < i1) {
      Un = uR[i0]; SCn = scR[i0];
      h0n = h0_in[colR[i0]*16 + c];
    }
    for (int i = i0; i < i1; i += 4) {
      float4 U = Un; float2 SC = SCn;
      float h0c = h0n;
      if (i+4 < i1) {
        Un = uR[i+4]; SCn = scR[i+4];
        h0n = h0_in[colR[i+4]*16 + c];
      }
      // fused Chebyshev + w-dot (no rad[] array)
      float Ki = KRADf * U.w;
      float tc = 2.f * SC.y;
      float sprev = 0.f, s = SC.x;
      float w0 = b0v, w1 = b1v, w2 = b2v;
      #pragma unroll
      for (int k = 0; k < 8; k++) {
        float rad = Ki * s;
        w0 += rad*wr0[k]; w1 += rad*wr1[k]; w2 += rad*wr2[k];
        float sn = tc*s - sprev; sprev = s; s = sn;
      }
      float sh1[3], sh2[5];
      sh_from_u(U.x, U.y, U.z, sh1, sh2);
      acc0 += w0*h0c;
      float wh1 = w1*h0c, wh2 = w2*h0c;
      #pragma unroll
      for (int m = 0; m < 3; m++) acc1[m] += wh1*sh1[m];
      #pragma unroll
      for (int m = 0; m < 5; m++) acc2[m] += wh2*sh2[m];
    }
    acc0 = xgrp_sum(acc0);
    #pragma unroll
    for (int m = 0; m < 3; m++) acc1[m] = xgrp_sum(acc1[m]);
    #pragma unroll
    for (int m = 0; m < 5; m++) acc2[m] = xgrp_sum(acc2[m]);
    if (g == 0) {
      a0[n*16 + c] = acc0;
      #pragma unroll
      for (int m = 0; m < 3; m++) a1[n*48 + c*3 + m] = acc1[m];
      #pragma unroll
      for (int m = 0; m < 5; m++) a2[n*80 + c*5 + m] = acc2[m];
    }
  }
}

// ---------------------------------------------------------------------------
// Forward block 1 (last) — persistent wave per node, 16-lane (r0 layout).
// ---------------------------------------------------------------------------
__global__ void k_fwd_b1(const float* __restrict__ Wr, const float* __restrict__ br,
                         const float* __restrict__ h0_in, const float* __restrict__ h1_in,
                         const float* __restrict__ h2_in,
                         const float4* __restrict__ uR, const float2* __restrict__ scR,
                         const int* __restrict__ colR,
                         const int* __restrict__ start_row, const int* __restrict__ deg_row,
                         float* __restrict__ a0, int N)
{
  int wid = (blockIdx.x * blockDim.x + threadIdx.x) >> 6;
  int nw  = (gridDim.x * blockDim.x) >> 6;
  int lane = threadIdx.x & 63;
  int g = lane >> 4, c = lane & 15;
  float wr0[8], wr3[8], wr4[8];
  #pragma unroll
  for (int k = 0; k < 8; k++) {
    wr0[k] = Wr[k*80 + c];
    wr3[k] = Wr[k*80 + 48 + c];
    wr4[k] = Wr[k*80 + 64 + c];
  }
  float b0v = br[c], b3v = br[48 + c], b4v = br[64 + c];

  for (int n = wid; n < N; n += nw) {
    float acc0 = 0.f;
    int i0 = start_row[n] + g, i1 = start_row[n] + deg_row[n];
    float4 Un = {0,0,0,0}; float2 SCn = {0,0};
    float h0n = 0.f, h1n[3] = {0,0,0}, h2n[5] = {0,0,0,0,0};
    if (i0 < i1) {
      int col = colR[i0];
      Un = uR[i0]; SCn = scR[i0];
      h0n = h0_in[col*16 + c];
      #pragma unroll
      for (int m = 0; m < 3; m++) h1n[m] = h1_in[col*48 + c*3 + m];
      #pragma unroll
      for (int m = 0; m < 5; m++) h2n[m] = h2_in[col*80 + c*5 + m];
    }
    for (int i = i0; i < i1; i += 4) {
      float4 U = Un; float2 SC = SCn;
      float h0c = h0n;
      float h1c[3], h2c[5];
      #pragma unroll
      for (int m = 0; m < 3; m++) h1c[m] = h1n[m];
      #pragma unroll
      for (int m = 0; m < 5; m++) h2c[m] = h2n[m];
      if (i+4 < i1) {
        int col = colR[i+4];
        Un = uR[i+4]; SCn = scR[i+4];
        h0n = h0_in[col*16 + c];
        #pragma unroll
        for (int m = 0; m < 3; m++) h1n[m] = h1_in[col*48 + c*3 + m];
        #pragma unroll
        for (int m = 0; m < 5; m++) h2n[m] = h2_in[col*80 + c*5 + m];
      }
      // fused Chebyshev + w-dot
      float Ki = KRADf * U.w;
      float tc = 2.f * SC.y;
      float sprev = 0.f, s = SC.x;
      float w0 = b0v, w3 = b3v, w4 = b4v;
      #pragma unroll
      for (int k = 0; k < 8; k++) {
        float rad = Ki * s;
        w0 += rad*wr0[k]; w3 += rad*wr3[k]; w4 += rad*wr4[k];
        float sn = tc*s - sprev; sprev = s; s = sn;
      }
      float sh1[3], sh2[5];
      sh_from_u(U.x, U.y, U.z, sh1, sh2);
      float S1 = 0.f, S2 = 0.f;
      #pragma unroll
      for (int m = 0; m < 3; m++) S1 += h1c[m]*sh1[m];
      #pragma unroll
      for (int m = 0; m < 5; m++) S2 += h2c[m]*sh2[m];
      acc0 += w0*h0c + w3*S1 + w4*S2;
    }
    acc0 = xgrp_sum(acc0);
    if (g == 0) a0[n*16 + c] = acc0;
  }
}

// ---------------------------------------------------------------------------
// Node update (block 0 only): h_out = h_in + a @ U
// ---------------------------------------------------------------------------
__global__ void k_node_update(const float* __restrict__ h0_in,
                              const float* __restrict__ a0, const float* __restrict__ a1,
                              const float* __restrict__ a2,
                              const float* __restrict__ U,
                              float* __restrict__ h0_out, float* __restrict__ h1_out,
                              float* __restrict__ h2_out, int N)
{
  int idx = blockIdx.x * blockDim.x + threadIdx.x;
  int n = idx >> 4, d = idx & 15;
  if (n >= N) return;
  const float* U0 = U;
  const float* U1 = U + 256;
  const float* U2 = U + 512;
  float s = h0_in[n*16 + d];
  #pragma unroll
  for (int c = 0; c < 16; c++) s += a0[n*16 + c] * U0[c*16 + d];
  h0_out[n*16 + d] = s;
  float v1[3] = {0.f, 0.f, 0.f};
  #pragma unroll
  for (int c = 0; c < 16; c++) {
    float u = U1[c*16 + d];
    #pragma unroll
    for (int m = 0; m < 3; m++) v1[m] += a1[n*48 + c*3 + m] * u;
  }
  #pragma unroll
  for (int m = 0; m < 3; m++) h1_out[n*48 + d*3 + m] = v1[m];
  float v2[5] = {0.f, 0.f, 0.f, 0.f, 0.f};
  #pragma unroll
  for (int c = 0; c < 16; c++) {
    float u = U2[c*16 + d];
    #pragma unroll
    for (int m = 0; m < 5; m++) v2[m] += a2[n*80 + c*5 + m] * u;
  }
  #pragma unroll
  for (int m = 0; m < 5; m++) h2_out[n*80 + d*5 + m] = v2[m];
}

// ---------------------------------------------------------------------------
// Readout fwd + bwd fused (unchanged).
// ---------------------------------------------------------------------------
__global__ void __launch_bounds__(256, 1)
k_readout_bwd(const float* __restrict__ h0s1, const float* __restrict__ a0in,
              const float* __restrict__ W_read,
              const float* __restrict__ W1, const float* __restrict__ b1,
              const float* __restrict__ W2, const float* __restrict__ b2,
              const float* __restrict__ U0b1,
              float* __restrict__ g0, float* __restrict__ ga0,
              float* __restrict__ partials, int N)
{
  __shared__ float sWr[256], sW1[256], sU[256], sb1[16], sW2[16], sb2;
  __shared__ float swave[4];
  {
    int t = threadIdx.x;
    if (t < 256) { sWr[t] = W_read[t]; sW1[t] = W1[t]; sU[t] = U0b1[t]; }
    if (t < 16)  { sb1[t] = b1[t]; sW2[t] = W2[t]; }
    if (t == 0)  sb2 = b2[0];
  }
  __syncthreads();
  int n = blockIdx.x * blockDim.x + threadIdx.x;
  float site = 0.f;
  if (n < N) {
    float h[16], av[16], inv[16], dt[16], g0v[16];
    #pragma unroll
    for (int d = 0; d < 16; d++) av[d] = a0in[n*16 + d];
    #pragma unroll
    for (int d = 0; d < 16; d++) {
      float s = h0s1[n*16 + d];
      #pragma unroll
      for (int cc = 0; cc < 16; cc++) s += av[cc] * sU[cc*16 + d];
      h[d] = s;
    }
    #pragma unroll
    for (int j = 0; j < 16; j++) {
      float s = 0.f;
      #pragma unroll
      for (int d = 0; d < 16; d++) s += h[d] * sWr[d*16 + j];
      inv[j] = s;
    }
    site = sb2;
    #pragma unroll
    for (int c = 0; c < 16; c++) {
      float t = sb1[c];
      #pragma unroll
      for (int j = 0; j < 16; j++) t += inv[j] * sW1[j*16 + c];
      float sg = 1.f / (1.f + expf(-t));
      float w2v = sW2[c];
      site += t * sg * w2v;
      dt[c] = w2v * sg * (1.f + t * (1.f - sg));
    }
    float dinv[16];
    #pragma unroll
    for (int j = 0; j < 16; j++) {
      float s = 0.f;
      #pragma unroll
      for (int c = 0; c < 16; c++) s += dt[c] * sW1[j*16 + c];
      dinv[j] = s;
    }
    #pragma unroll
    for (int d = 0; d < 16; d++) {
      float s = 0.f;
      #pragma unroll
      for (int j = 0; j < 16; j++) s += dinv[j] * sWr[d*16 + j];
      g0v[d] = s;
      g0[n*16 + d] = s;
    }
    #pragma unroll
    for (int c = 0; c < 16; c++) {
      float s = 0.f;
      #pragma unroll
      for (int d = 0; d < 16; d++) s += g0v[d] * sU[c*16 + d];
      ga0[n*16 + c] = s;
    }
  }
  #pragma unroll
  for (int off = 32; off; off >>= 1) site += __shfl_down(site, off, 64);
  int wave = threadIdx.x >> 6;
  if ((threadIdx.x & 63) == 0) swave[wave] = site;
  __syncthreads();
  if (threadIdx.x == 0)
    partials[blockIdx.x] = swave[0] + swave[1] + swave[2] + swave[3];
}

// Sum per-block partials into energy (single tiny block).
__global__ void k_energy(const float* __restrict__ partials, int nb,
                         float* __restrict__ energy)
{
  int t = threadIdx.x;           // 128 threads (2 waves)
  float s = 0.f;
  for (int i = t; i < nb; i += 128) s += partials[i];
  #pragma unroll
  for (int off = 32; off; off >>= 1) s += __shfl_down(s, off, 64);
  __shared__ float sw[2];
  if ((t & 63) == 0) sw[t >> 6] = s;
  __syncthreads();
  if (t == 0) energy[0] = sw[0] + sw[1];
}

// ---------------------------------------------------------------------------
// ga = g @ U^T (full, for block 0 backward)
// ---------------------------------------------------------------------------
__global__ void k_ga(const float* __restrict__ g0, const float* __restrict__ g1,
                     const float* __restrict__ g2, const float* __restrict__ U,
                     float* __restrict__ ga0, float* __restrict__ ga1, float* __restrict__ ga2,
                     int N)
{
  int idx = blockIdx.x * blockDim.x + threadIdx.x;
  int n = idx >> 4, c = idx & 15;
  if (n >= N) return;
  const float* U0 = U;
  const float* U1 = U + 256;
  const float* U2 = U + 512;
  float s = 0.f;
  #pragma unroll
  for (int d = 0; d < 16; d++) s += g0[n*16 + d] * U0[c*16 + d];
  ga0[n*16 + c] = s;
  float v1[3] = {0.f, 0.f, 0.f};
  #pragma unroll
  for (int d = 0; d < 16; d++) {
    float u = U1[c*16 + d];
    #pragma unroll
    for (int m = 0; m < 3; m++) v1[m] += g1[n*48 + d*3 + m] * u;
  }
  #pragma unroll
  for (int m = 0; m < 3; m++) ga1[n*48 + c*3 + m] = v1[m];
  float v2[5] = {0.f, 0.f, 0.f, 0.f, 0.f};
  #pragma unroll
  for (int d = 0; d < 16; d++) {
    float u = U2[c*16 + d];
    #pragma unroll
    for (int m = 0; m < 5; m++) v2[m] += g2[n*80 + d*5 + m] * u;
  }
  #pragma unroll
  for (int m = 0; m < 5; m++) ga2[n*80 + c*5 + m] = v2[m];
}

// ---------------------------------------------------------------------------
// Backward block 1, col-centric — persistent wave per node, 16-lane.
// Merged k-loop: w/t/P/Q in one pass; gr = inv_r*(KPI5*P - Q).
// ---------------------------------------------------------------------------
__global__ void k_bwd_b1_col(const float* __restrict__ Wr, const float* __restrict__ br,
                             const float* __restrict__ h0_in, const float* __restrict__ h1_in,
                             const float* __restrict__ h2_in,
                             const float* __restrict__ ga0,
                             const float4* __restrict__ uC, const float2* __restrict__ scC,
                             const int* __restrict__ rowC,
                             const int* __restrict__ start_col, const int* __restrict__ deg_col,
                             float* __restrict__ g0, float* __restrict__ g1, float* __restrict__ g2,
                             float* __restrict__ dv_col, int N)
{
  int wid = (blockIdx.x * blockDim.x + threadIdx.x) >> 6;
  int nw  = (gridDim.x * blockDim.x) >> 6;
  int lane = threadIdx.x & 63;
  int g = lane >> 4, c = lane & 15;
  float wr0[8], wr3[8], wr4[8];
  #pragma unroll
  for (int k = 0; k < 8; k++) {
    wr0[k] = Wr[k*80 + c];
    wr3[k] = Wr[k*80 + 48 + c];
    wr4[k] = Wr[k*80 + 64 + c];
  }
  float b0v = br[c], b3v = br[48 + c], b4v = br[64 + c];

  for (int n = wid; n < N; n += nw) {
    float h0c = h0_in[n*16 + c];
    float h1c[3], h2c[5];
    #pragma unroll
    for (int m = 0; m < 3; m++) h1c[m] = h1_in[n*48 + c*3 + m];
    #pragma unroll
    for (int m = 0; m < 5; m++) h2c[m] = h2_in[n*80 + c*5 + m];

    float accg0 = 0.f, accg1[3] = {0.f,0.f,0.f}, accg2[5] = {0.f,0.f,0.f,0.f,0.f};

    int i0 = start_col[n] + g, i1 = start_col[n] + deg_col[n];
    float4 Un = {0,0,0,0}; float2 SCn = {0,0};
    float dm0n = 0.f;
    if (i0 < i1) {
      Un = uC[i0]; SCn = scC[i0];
      dm0n = ga0[rowC[i0]*16 + c];
    }
    for (int i = i0; i < i1; i += 4) {
      float4 U = Un; float2 SC = SCn;
      float dm0 = dm0n;
      if (i+4 < i1) {
        Un = uC[i+4]; SCn = scC[i+4];
        dm0n = ga0[rowC[i+4]*16 + c];
      }
      float ux = U.x, uy = U.y, uz = U.z, inv_r = U.w;
      float sh1[3], sh2[5];
      sh_from_u(ux, uy, uz, sh1, sh2);

      float S1 = 0.f, S2 = 0.f;
      #pragma unroll
      for (int m = 0; m < 3; m++) S1 += h1c[m]*sh1[m];
      #pragma unroll
      for (int m = 0; m < 5; m++) S2 += h2c[m]*sh2[m];

      float dw0 = dm0 * h0c;
      float dw3 = dm0 * S1;
      float dw4 = dm0 * S2;

      // merged Chebyshev + w-dot + t-dot + P/Q (no rad/draddr arrays)
      float Ki = KRADf * inv_r;
      float tc = 2.f * SC.y;
      float sprev = 0.f, s = SC.x, cprev = 1.f, cc = SC.y;
      float w0 = b0v, w3 = b3v, w4 = b4v;
      float P = 0.f, Q = 0.f;
      #pragma unroll
      for (int k = 0; k < 8; k++) {
        float rad = Ki * s;
        w0 += rad*wr0[k]; w3 += rad*wr3[k]; w4 += rad*wr4[k];
        float t = dw0*wr0[k] + dw3*wr3[k] + dw4*wr4[k];
        P = fmaf(t*cc, (float)(k+1), P);
        Q = fmaf(t, rad, Q);
        float sn = tc*s - sprev; sprev = s; s = sn;
        float cn = tc*cc - cprev; cprev = cc; cc = cn;
      }

      float t3 = dm0 * w3, t4 = dm0 * w4;
      accg0 += dm0 * w0;
      #pragma unroll
      for (int m = 0; m < 3; m++) accg1[m] += t3 * sh1[m];
      #pragma unroll
      for (int m = 0; m < 5; m++) accg2[m] += t4 * sh2[m];

      float q1x = t3*h1c[0], q1y = t3*h1c[1], q1z = t3*h1c[2];
      float q0 = t4*h2c[0], q1 = t4*h2c[1], q2 = t4*h2c[2], q3 = t4*h2c[3], q4 = t4*h2c[4];
      float gr = (KPI5f*P - Q) * inv_r;
      float gux = SQRT3f*q1x + SQRT15f*(uy*q0 + uz*q3 + ux*q4);
      float guy = SQRT3f*q1y + SQRT15f*(ux*q0 + uz*q1 - uy*q4);
      float guz = SQRT3f*q1z + SQRT15f*uy*q1 + 3.f*SQRT5f*uz*q2 + SQRT15f*ux*q3;

      gr  = grp16_sum(gr);
      gux = grp16_sum(gux);
      guy = grp16_sum(guy);
      guz = grp16_sum(guz);

      if (c == 0) {
        float gdotu = gux*ux + guy*uy + guz*uz;
        dv_col[i*3+0] = gr*ux + (gux - gdotu*ux)*inv_r;
        dv_col[i*3+1] = gr*uy + (guy - gdotu*uy)*inv_r;
        dv_col[i*3+2] = gr*uz + (guz - gdotu*uz)*inv_r;
      }
    }
    accg0 = xgrp_sum(accg0);
    #pragma unroll
    for (int m = 0; m < 3; m++) accg1[m] = xgrp_sum(accg1[m]);
    #pragma unroll
    for (int m = 0; m < 5; m++) accg2[m] = xgrp_sum(accg2[m]);
    if (g == 0) {
      g0[n*16 + c] += accg0;
      #pragma unroll
      for (int m = 0; m < 3; m++) g1[n*48 + c*3 + m] = accg1[m];
      #pragma unroll
      for (int m = 0; m < 5; m++) g2[n*80 + c*5 + m] = accg2[m];
    }
  }
}

// ---------------------------------------------------------------------------
// Backward block 0, row-centric — persistent wave per node, 16-lane.
// Merged k-loop (w1,w2 + t-dot + P/Q in one pass).
// ---------------------------------------------------------------------------
__global__ void k_bwd_b0_row(const float* __restrict__ Wr, const float* __restrict__ br,
                             const float* __restrict__ h0_in,
                             const float* __restrict__ ga0, const float* __restrict__ ga1,
                             const float* __restrict__ ga2,
                             const float4* __restrict__ uR, const float2* __restrict__ scR,
                             const int* __restrict__ colR,
                             const int* __restrict__ start_row, const int* __restrict__ deg_row,
                             float* __restrict__ dv_row, int N)
{
  int wid = (blockIdx.x * blockDim.x + threadIdx.x) >> 6;
  int nw  = (gridDim.x * blockDim.x) >> 6;
  int lane = threadIdx.x & 63;
  int g = lane >> 4, c = lane & 15;
  float wr0[8], wr1[8], wr2[8];
  #pragma unroll
  for (int k = 0; k < 8; k++) {
    wr0[k] = Wr[k*80 + c];
    wr1[k] = Wr[k*80 + 16 + c];
    wr2[k] = Wr[k*80 + 32 + c];
  }
  float b1v = br[16 + c], b2v = br[32 + c];

  for (int n = wid; n < N; n += nw) {
    float dm0 = ga0[n*16 + c];
    float dm1[3], dm2[5];
    #pragma unroll
    for (int m = 0; m < 3; m++) dm1[m] = ga1[n*48 + c*3 + m];
    #pragma unroll
    for (int m = 0; m < 5; m++) dm2[m] = ga2[n*80 + c*5 + m];

    int i0 = start_row[n] + g, i1 = start_row[n] + deg_row[n];
    float4 Un = {0,0,0,0}; float2 SCn = {0,0};
    float h0n = 0.f;
    if (i0 < i1) {
      Un = uR[i0]; SCn = scR[i0];
      h0n = h0_in[colR[i0]*16 + c];
    }
    for (int i = i0; i < i1; i += 4) {
      float4 U = Un; float2 SC = SCn;
      float h0c = h0n;
      if (i+4 < i1) {
        Un = uR[i+4]; SCn = scR[i+4];
        h0n = h0_in[colR[i+4]*16 + c];
      }
      float ux = U.x, uy = U.y, uz = U.z, inv_r = U.w;
      float sh1[3], sh2[5];
      sh_from_u(ux, uy, uz, sh1, sh2);

      float T1 = 0.f, T2 = 0.f;
      #pragma unroll
      for (int m = 0; m < 3; m++) T1 += dm1[m]*sh1[m];
      #pragma unroll
      for (int m = 0; m < 5; m++) T2 += dm2[m]*sh2[m];

      float dw0 = dm0 * h0c;
      float dw1 = h0c * T1;
      float dw2 = h0c * T2;

      // merged Chebyshev + w-dot + t-dot + P/Q
      float Ki = KRADf * inv_r;
      float tc = 2.f * SC.y;
      float sprev = 0.f, s = SC.x, cprev = 1.f, cc = SC.y;
      float w1 = b1v, w2v = b2v;
      float P = 0.f, Q = 0.f;
      #pragma unroll
      for (int k = 0; k < 8; k++) {
        float rad = Ki * s;
        w1 += rad*wr1[k]; w2v += rad*wr2[k];
        float t = dw0*wr0[k] + dw1*wr1[k] + dw2*wr2[k];
        P = fmaf(t*cc, (float)(k+1), P);
        Q = fmaf(t, rad, Q);
        float sn = tc*s - sprev; sprev = s; s = sn;
        float cn = tc*cc - cprev; cprev = cc; cc = cn;
      }

      float w1h = w1*h0c, w2h = w2v*h0c;
      float q1x = dm1[0]*w1h, q1y = dm1[1]*w1h, q1z = dm1[2]*w1h;
      float q0 = dm2[0]*w2h, q1 = dm2[1]*w2h, q2 = dm2[2]*w2h, q3 = dm2[3]*w2h, q4 = dm2[4]*w2h;

      float gr = (KPI5f*P - Q) * inv_r;
      float gux = SQRT3f*q1x + SQRT15f*(uy*q0 + uz*q3 + ux*q4);
      float guy = SQRT3f*q1y + SQRT15f*(ux*q0 + uz*q1 - uy*q4);
      float guz = SQRT3f*q1z + SQRT15f*uy*q1 + 3.f*SQRT5f*uz*q2 + SQRT15f*ux*q3;

      gr  = grp16_sum(gr);
      gux = grp16_sum(gux);
      guy = grp16_sum(guy);
      guz = grp16_sum(guz);

      if (c == 0) {
        float gdotu = gux*ux + guy*uy + guz*uz;
        dv_row[i*3+0] = gr*ux + (gux - gdotu*ux)*inv_r;
        dv_row[i*3+1] = gr*uy + (guy - gdotu*uy)*inv_r;
        dv_row[i*3+2] = gr*uz + (guz - gdotu*uz)*inv_r;
      }
    }
  }
}

// ---------------------------------------------------------------------------
// Force assembly: 16 lanes per node.
// ---------------------------------------------------------------------------
__global__ void k_force(const int* __restrict__ start_row, const int* __restrict__ deg_row,
                        const int* __restrict__ cposR,
                        const int* __restrict__ start_col, const int* __restrict__ deg_col,
                        const int* __restrict__ rposC,
                        const float* __restrict__ dv_col, const float* __restrict__ dv_row,
                        float* __restrict__ force, int N)
{
  int idx = blockIdx.x * blockDim.x + threadIdx.x;
  int n = idx >> 4, l = idx & 15;
  if (n >= N) return;
  float fx = 0.f, fy = 0.f, fz = 0.f;
  int c0 = start_col[n], c1 = c0 + deg_col[n];
  for (int i = c0 + l; i < c1; i += 16) {
    int rp = rposC[i];
    fx += dv_col[i*3+0] + dv_row[rp*3+0];
    fy += dv_col[i*3+1] + dv_row[rp*3+1];
    fz += dv_col[i*3+2] + dv_row[rp*3+2];
  }
  int r0 = start_row[n], r1 = r0 + deg_row[n];
  for (int i = r0 + l; i < r1; i += 16) {
    int cp = cposR[i];
    fx -= dv_row[i*3+0] + dv_col[cp*3+0];
    fy -= dv_row[i*3+1] + dv_col[cp*3+1];
    fz -= dv_row[i*3+2] + dv_col[cp*3+2];
  }
  fx = grp16_sum(fx); fy = grp16_sum(fy); fz = grp16_sum(fz);
  if (l == 0) {
    force[n*3+0] = fx; force[n*3+1] = fy; force[n*3+2] = fz;
  }
}

// ---------------------------------------------------------------------------
extern "C" void kernel_launch(void* const* d_in, const int* in_sizes, int n_in,
                              void* d_out, int out_size, void* d_ws, size_t ws_size,
                              hipStream_t stream)
{
  const float* pos    = (const float*)d_in[0];
  const int*   z      = (const int*)  d_in[1];
  const int*   ei     = (const int*)  d_in[2];
  const float* emb    = (const float*)d_in[3];
  const float* W_init = (const float*)d_in[4];
  const float* Wr     = (const float*)d_in[5];   // (2, 8, 80)
  const float* br     = (const float*)d_in[6];   // (2, 80)
  const float* W_out  = (const float*)d_in[7];   // (2, 3, 16, 16)
  const float* W_read = (const float*)d_in[8];
  const float* W1     = (const float*)d_in[9];
  const float* b1     = (const float*)d_in[10];
  const float* W2     = (const float*)d_in[11];
  const float* b2     = (const float*)d_in[12];

  const int N = in_sizes[0] / 3;
  const int E = in_sizes[2] / 2;

  const int BLK = 256;
  const int NB_READOUT = cdiv(N, BLK);
  // Persistent grid for wave-per-node kernels.
  const int PBLK = (N < 8192) ? cdiv(N, 4) : 2048;

  float* f = (float*)d_ws;
  float4* uR  = (float4*)f; f += (size_t)E*4;
  float4* uC  = (float4*)f; f += (size_t)E*4;
  float2* scR = (float2*)f; f += (size_t)E*2;
  float2* scC = (float2*)f; f += (size_t)E*2;
  float* h0_s0 = f; f += (size_t)N*16;
  float* h0_s1 = f; f += (size_t)N*16;
  float* h1_s1 = f; f += (size_t)N*48;
  float* h2_s1 = f; f += (size_t)N*80;
  float* a0    = f; f += (size_t)N*16;   // block-0 agg, then block-1 agg, then ga0_b0
  float* a1    = f; f += (size_t)N*48;   //                                 ga1_b0
  float* a2    = f; f += (size_t)N*80;   //                                 ga2_b0
  float* ga0b1 = f; f += (size_t)N*16;   // readout's ga0 (dE/da0 block 1)
  float* g0    = f; f += (size_t)N*16;
  float* g1    = f; f += (size_t)N*48;
  float* g2    = f; f += (size_t)N*80;
  float* dv_c  = f; f += (size_t)E*3;    // dv from bwd b1, col order
  float* dv_r  = f; f += (size_t)E*3;    // dv from bwd b0, row order
  float* partials = f; f += (size_t)NB_READOUT;
  int* ip = (int*)f;
  int* cursors   = ip; ip += 2;          // cursors+deg contiguous -> one memset
  int* deg_row   = ip; ip += N;
  int* deg_col   = ip; ip += N;
  int* start_row = ip; ip += N;
  int* start_col = ip; ip += N;
  int* cur_row   = ip; ip += N;
  int* cur_col   = ip; ip += N;
  int* colR      = ip; ip += E;
  int* cposR     = ip; ip += E;
  int* rowC      = ip; ip += E;
  int* rposC     = ip; ip += E;

  float* out    = (float*)d_out;
  float* energy = out;
  float* force  = out + 1;

  (void)hipMemsetAsync(cursors, 0, (size_t)(2 + 2*N) * sizeof(int), stream);

  // ---- CSR build (scan-free) + compact geometry in both orders ----
  k_hist<<<cdiv(E, BLK), BLK, 0, stream>>>(ei, E, deg_row, deg_col);
  k_alloc<<<cdiv(N, BLK), BLK, 0, stream>>>(deg_row, deg_col, start_row, cur_row,
                                            start_col, cur_col, cursors, N);
  k_scatter_geom<<<cdiv(E, BLK), BLK, 0, stream>>>(pos, ei, E, cur_row, cur_col,
                                                   uR, scR, uC, scC,
                                                   colR, cposR, rowC, rposC);

  k_node_init<<<cdiv(N, BLK), BLK, 0, stream>>>(emb, z, W_init, h0_s0, N);

  // ---- forward block 0 ----
  k_fwd_b0<<<PBLK, BLK, 0, stream>>>(Wr, br, h0_s0, uR, scR, colR,
                                     start_row, deg_row, a0, a1, a2, N);
  k_node_update<<<cdiv(N*16, BLK), BLK, 0, stream>>>(h0_s0, a0, a1, a2,
                                                     W_out, h0_s1, h1_s1, h2_s1, N);

  // ---- forward block 1 (h0_s2 folded into readout) ----
  k_fwd_b1<<<PBLK, BLK, 0, stream>>>(Wr + 640, br + 80,
                                     h0_s1, h1_s1, h2_s1, uR, scR, colR,
                                     start_row, deg_row, a0, N);

  // ---- readout fwd + bwd (includes block-1 h0 update; emits g0, ga0b1) ----
  k_readout_bwd<<<NB_READOUT, BLK, 0, stream>>>(h0_s1, a0, W_read, W1, b1, W2, b2,
                                                W_out + 768, g0, ga0b1, partials, N);
  k_energy<<<1, 128, 0, stream>>>(partials, NB_READOUT, energy);

  // ---- backward block 1 ----
  k_bwd_b1_col<<<PBLK, BLK, 0, stream>>>(Wr + 640, br + 80,
                                         h0_s1, h1_s1, h2_s1, ga0b1,
                                         uC, scC, rowC, start_col, deg_col,
                                         g0, g1, g2, dv_c, N);

  // ---- backward block 0 ----
  k_ga<<<cdiv(N*16, BLK), BLK, 0, stream>>>(g0, g1, g2, W_out, a0, a1, a2, N);
  k_bwd_b0_row<<<PBLK, BLK, 0, stream>>>(Wr, br, h0_s0,
                                         a0, a1, a2, uR, scR, colR,
                                         start_row, deg_row, dv_r, N);

  // ---- force assembly ----
  k_force<<<cdiv(N*16, BLK), BLK, 0, stream>>>(start_row, deg_row, cposR,
                                               start_col, deg_col, rposC,
                                               dv_c, dv_r, force, N);
}